// Round 3
// baseline (766.754 us; speedup 1.0000x reference)
//
#include <hip/hip_runtime.h>
#include <math.h>

#define DM    1024
#define NH    16
#define DH    64
#define DI    4096
#define QL    1024
#define MLN   1024
#define BATCH 2
#define KL    2048   // QL + MLN

typedef unsigned short u16;
typedef short s16x8 __attribute__((ext_vector_type(8)));
typedef float f32x4 __attribute__((ext_vector_type(4)));

__device__ __forceinline__ u16 f2bf(float f) {
    union { float f; unsigned u; } v; v.f = f;
    unsigned u = v.u;
    unsigned r = (u + 0x7FFFu + ((u >> 16) & 1u)) >> 16;
    return (u16)r;
}
__device__ __forceinline__ float bf2f(u16 h) {
    union { unsigned u; float f; } v; v.u = ((unsigned)h) << 16;
    return v.f;
}

__device__ __forceinline__ void gl2lds16(const void* g, void* l) {
    __builtin_amdgcn_global_load_lds(
        (const __attribute__((address_space(1))) void*)g,
        (__attribute__((address_space(3))) void*)l, 16, 0, 0);
}

// ---------------- vectorized fp32 -> bf16 ----------------
__global__ __launch_bounds__(256) void cvt4(const float* __restrict__ x,
                                            u16* __restrict__ y, int n4) {
    int i = blockIdx.x * 256 + threadIdx.x;
    int stride = gridDim.x * 256;
    for (; i < n4; i += stride) {
        float4 v = ((const float4*)x)[i];
        ushort4 o = {f2bf(v.x), f2bf(v.y), f2bf(v.z), f2bf(v.w)};
        ((ushort4*)y)[i] = o;
    }
}

// cat in batch-major layout: cat[b][kpos][:] from mems[k][b][:] / w[i][b][:]
__global__ __launch_bounds__(256) void cvt_cat(const float* __restrict__ mems,
                                               const float* __restrict__ w,
                                               u16* __restrict__ cat) {
    int id = blockIdx.x * 256 + threadIdx.x;     // 4096 rows * 256 chunks
    int c4 = (id & 255) * 4;
    int row = id >> 8;
    int b = row >> 11, kpos = row & 2047;
    const float* src = (kpos < QL)
        ? mems + ((size_t)kpos * BATCH + b) * DM + c4
        : w + ((size_t)(kpos - QL) * BATCH + b) * DM + c4;
    float4 v = *(const float4*)src;
    ushort4 o = {f2bf(v.x), f2bf(v.y), f2bf(v.z), f2bf(v.w)};
    *(ushort4*)(cat + (size_t)row * DM + c4) = o;
}

// rb2[n][jj] = 0.125*(r_bias[jj,n] - r_w_bias[n,:].dot(r_emb[jj,n,:]))
__global__ __launch_bounds__(256) void rb2_prep(const float* __restrict__ r_emb,
                                                const float* __restrict__ r_w_bias,
                                                const float* __restrict__ r_bias,
                                                float* __restrict__ rb2) {
    int id = blockIdx.x * 256 + threadIdx.x;
    if (id >= NH * KL) return;
    int n = id >> 11, jj = id & (KL - 1);
    float dot = 0.0f;
#pragma unroll 8
    for (int d = 0; d < 64; ++d)
        dot += r_w_bias[n * 64 + d] * r_emb[(size_t)jj * (NH * DH) + n * 64 + d];
    rb2[n * KL + jj] = 0.125f * (r_bias[jj * NH + n] - dot);
}

// ---------------- staged GEMM: C[M,*] = A[M,K] * B[*,K]^T ----------------
// BM=128, BK=32. FLAGS: 1=bf16 out, 2=bias, 4=relu, 8=V-split (QKV epilogue).
// V-split: cols<2048 -> Cb row-major (stride N_out=2048); cols>=2048 -> Vt_out
// at [((b*16+n)*64+d)*2048 + kpos] (pre-transposed V), b=row>>11, kpos=row&2047.
template <int BN, int FLAGS>
__global__ __launch_bounds__(256) void gemm_s(const u16* __restrict__ A,
                                              const u16* __restrict__ B,
                                              float* __restrict__ Cf,
                                              u16* __restrict__ Cb,
                                              u16* __restrict__ Vt_out,
                                              const float* __restrict__ bias,
                                              int M, int N_out, int K) {
    constexpr int WN = BN / 2;       // per-wave n extent
    constexpr int TN = WN / 16;      // 4 or 2
    __shared__ u16 As[128 * 32];
    __shared__ u16 Bs[BN * 32];

    const int t = threadIdx.x;
    const int lane = t & 63, wid = t >> 6;
    const int wm = wid >> 1, wn = wid & 1;
    const int lr = lane & 15, quad = lane >> 4;
    const int m_blk = blockIdx.y * 128;
    const int n_blk = blockIdx.x * BN;
    const int srow = t >> 2;             // 0..63 staging row
    const int skc  = (t & 3) * 8;        // staging k-chunk (elements)

    f32x4 acc[4][TN];
#pragma unroll
    for (int i = 0; i < 4; ++i)
#pragma unroll
        for (int j = 0; j < TN; ++j) acc[i][j] = (f32x4)0.0f;

    for (int k0 = 0; k0 < K; k0 += 32) {
        __syncthreads();
        gl2lds16(A + (size_t)(m_blk + srow) * K + k0 + skc, As + wid * 512);
        gl2lds16(A + (size_t)(m_blk + 64 + srow) * K + k0 + skc, As + 2048 + wid * 512);
        gl2lds16(B + (size_t)(n_blk + srow) * K + k0 + skc, Bs + wid * 512);
        if (BN == 128)
            gl2lds16(B + (size_t)(n_blk + 64 + srow) * K + k0 + skc, Bs + 2048 + wid * 512);
        __syncthreads();

        s16x8 a[4], b[TN];
#pragma unroll
        for (int i = 0; i < 4; ++i)
            a[i] = *(const s16x8*)(As + (wm * 64 + i * 16 + lr) * 32 + quad * 8);
#pragma unroll
        for (int j = 0; j < TN; ++j)
            b[j] = *(const s16x8*)(Bs + (wn * WN + j * 16 + lr) * 32 + quad * 8);
#pragma unroll
        for (int i = 0; i < 4; ++i)
#pragma unroll
            for (int j = 0; j < TN; ++j)
                acc[i][j] = __builtin_amdgcn_mfma_f32_16x16x32_bf16(
                    a[i], b[j], acc[i][j], 0, 0, 0);
    }

#pragma unroll
    for (int i = 0; i < 4; ++i) {
#pragma unroll
        for (int j = 0; j < TN; ++j) {
            int row0 = m_blk + wm * 64 + i * 16 + quad * 4;
            int col  = n_blk + wn * WN + j * 16 + lr;
            if ((FLAGS & 8) && col >= 2048) {
                // V part: pre-transposed write, 4 consecutive kpos in one store
                int d = col & 63, n = (col >> 6) & 15;
                int b_ = row0 >> 11, kpos = row0 & 2047;
                ushort4 o = {f2bf(acc[i][j][0]), f2bf(acc[i][j][1]),
                             f2bf(acc[i][j][2]), f2bf(acc[i][j][3])};
                *(ushort4*)(Vt_out + ((size_t)((b_ * 16 + n) * 64 + d)) * KL + kpos) = o;
            } else {
                float bv = (FLAGS & 2) ? bias[col] : 0.0f;
#pragma unroll
                for (int r = 0; r < 4; ++r) {
                    float v = acc[i][j][r] + bv;
                    if (FLAGS & 4) v = fmaxf(v, 0.0f);
                    size_t idx = (size_t)(row0 + r) * N_out + col;
                    if (FLAGS & 1) Cb[idx] = f2bf(v);
                    else           Cf[idx] = v;
                }
            }
        }
    }
}

// ---------------- flash attention, XCD-local, V^T from global ----------------
// 1-D grid 512: bn = idx%32 (so all i-blocks of a head share an XCD's L2),
// i0 = (idx/32)*64. Wqk: [b*2048+kpos][2048] (Q cols 0..1023, K cols 1024..2047).
// Vt: [ (b*16+n)*64 + d ][2048] pre-transposed V.
__global__ __launch_bounds__(256, 3) void flash_attn(
    const u16* __restrict__ Wqk, const u16* __restrict__ Vt_g,
    const u16* __restrict__ r_bf, const float* __restrict__ r_w_bias,
    const float* __restrict__ rb2, u16* __restrict__ av) {
    const int bn = blockIdx.x & 31;
    const int i0 = (blockIdx.x >> 5) * 64;
    const int b = bn >> 4, n = bn & 15;
    const int t = threadIdx.x;
    const int lane = t & 63, w = t >> 6;
    const int lr = lane & 15, quad = lane >> 4;

    __shared__ char smem[47616];
    u16* Bt = (u16*)smem;                       // [64][196] shifted-bias tile
    u16* Pw = (u16*)(smem + 25088) + w * 2560;  // [64][40] probs, per wave
    float* m_s = (float*)(smem + 45568);        // [4][64]
    float* l_s = m_s + 256;                     // [4][64]
    float* Oacc = (float*)smem;                 // [64][66] overlay (final merge)

    const u16* Vh = Vt_g + (size_t)bn * 64 * KL;

    // qw = bf16(0.125*(q + r_w_bias))
    s16x8 qw[4][2];
#pragma unroll
    for (int mt = 0; mt < 4; ++mt)
#pragma unroll
        for (int ks = 0; ks < 2; ++ks) {
            int i = i0 + mt * 16 + lr;
            const u16* qp = Wqk + (size_t)(b * KL + QL + i) * 2048 + n * 64 + ks * 32 + quad * 8;
            s16x8 qv = *(const s16x8*)qp;
            s16x8 o;
#pragma unroll
            for (int k = 0; k < 8; ++k) {
                float f = bf2f((u16)qv[k]) + r_w_bias[n * 64 + ks * 32 + quad * 8 + k];
                o[k] = (short)f2bf(f * 0.125f);
            }
            qw[mt][ks] = o;
        }

    f32x4 O[4][4];
    float m_r[4][4], l_r[4][4];
#pragma unroll
    for (int mt = 0; mt < 4; ++mt)
#pragma unroll
        for (int x = 0; x < 4; ++x) {
            O[mt][x] = (f32x4)0.0f;
            m_r[mt][x] = -INFINITY;
            l_r[mt][x] = 0.0f;
        }

    const int jend = i0 + 64 + MLN;
    for (int j0 = 0; j0 < jend; j0 += 128) {
        __syncthreads();   // prior iter's Bt reads complete

        // ---- Bt tile: Bt[row][col] = qw . r[jjbase+col] (+rb2) ----
        const int jjbase = j0 + 960 - i0;   // jjloc = colj + 63 - row
        {
            f32x4 bacc[4][3];
#pragma unroll
            for (int mt = 0; mt < 4; ++mt)
#pragma unroll
                for (int c = 0; c < 3; ++c) bacc[mt][c] = (f32x4)0.0f;
#pragma unroll
            for (int ks = 0; ks < 2; ++ks) {
                s16x8 rf[3];
#pragma unroll
                for (int c = 0; c < 3; ++c) {
                    int jj = jjbase + (w * 3 + c) * 16 + lr;
                    jj = jj < 0 ? 0 : (jj > KL - 1 ? KL - 1 : jj);
                    rf[c] = *(const s16x8*)(r_bf + (size_t)jj * DM + n * 64 + ks * 32 + quad * 8);
                }
#pragma unroll
                for (int mt = 0; mt < 4; ++mt)
#pragma unroll
                    for (int c = 0; c < 3; ++c)
                        bacc[mt][c] = __builtin_amdgcn_mfma_f32_16x16x32_bf16(
                            qw[mt][ks], rf[c], bacc[mt][c], 0, 0, 0);
            }
            float rbv[3];
#pragma unroll
            for (int c = 0; c < 3; ++c) {
                int jj = jjbase + (w * 3 + c) * 16 + lr;
                rbv[c] = (jj >= 0 && jj < KL) ? rb2[n * KL + jj] : 0.0f;
            }
#pragma unroll
            for (int mt = 0; mt < 4; ++mt)
#pragma unroll
                for (int c = 0; c < 3; ++c) {
                    int col = (w * 3 + c) * 16 + lr;
#pragma unroll
                    for (int r = 0; r < 4; ++r) {
                        int row = mt * 16 + quad * 4 + r;
                        Bt[row * 196 + col] = f2bf(bacc[mt][c][r] + rbv[c]);
                    }
                }
        }
        __syncthreads();

        // ---- S = qw . K^T for this wave's 32 cols ----
        f32x4 sacc[4][2];
#pragma unroll
        for (int mt = 0; mt < 4; ++mt)
#pragma unroll
            for (int nt = 0; nt < 2; ++nt) sacc[mt][nt] = (f32x4)0.0f;
#pragma unroll
        for (int ks = 0; ks < 2; ++ks) {
            s16x8 kf[2];
#pragma unroll
            for (int nt = 0; nt < 2; ++nt) {
                int j = j0 + w * 32 + nt * 16 + lr;
                kf[nt] = *(const s16x8*)(Wqk + (size_t)(b * KL + j) * 2048 + 1024 + n * 64 + ks * 32 + quad * 8);
            }
#pragma unroll
            for (int mt = 0; mt < 4; ++mt)
#pragma unroll
                for (int nt = 0; nt < 2; ++nt)
                    sacc[mt][nt] = __builtin_amdgcn_mfma_f32_16x16x32_bf16(
                        qw[mt][ks], kf[nt], sacc[mt][nt], 0, 0, 0);
        }
        // ---- add shifted bias, mask ----
#pragma unroll
        for (int mt = 0; mt < 4; ++mt)
#pragma unroll
            for (int nt = 0; nt < 2; ++nt) {
                int colj = w * 32 + nt * 16 + lr;
                int j = j0 + colj;
#pragma unroll
                for (int r = 0; r < 4; ++r) {
                    int row = mt * 16 + quad * 4 + r;
                    int i = i0 + row;
                    int jjloc = colj + 63 - row;
                    float v = sacc[mt][nt][r] + bf2f(Bt[row * 196 + jjloc]);
                    sacc[mt][nt][r] = (j <= i + MLN) ? v : -INFINITY;
                }
            }
        // ---- online softmax update ----
#pragma unroll
        for (int mt = 0; mt < 4; ++mt) {
            float rmax[4], al[4], ps[4];
#pragma unroll
            for (int r = 0; r < 4; ++r) rmax[r] = fmaxf(sacc[mt][0][r], sacc[mt][1][r]);
#pragma unroll
            for (int msk = 1; msk <= 8; msk <<= 1)
#pragma unroll
                for (int r = 0; r < 4; ++r)
                    rmax[r] = fmaxf(rmax[r], __shfl_xor(rmax[r], msk, 64));
#pragma unroll
            for (int r = 0; r < 4; ++r) {
                float mo = m_r[mt][r];
                float mn = fmaxf(mo, rmax[r]);
                float a = __expf(mo - mn);
                m_r[mt][r] = mn; al[r] = a;
#pragma unroll
                for (int nt = 0; nt < 4; ++nt) O[mt][nt][r] *= a;
                float p0 = __expf(sacc[mt][0][r] - mn);
                float p1 = __expf(sacc[mt][1][r] - mn);
                ps[r] = p0 + p1;
                int row = mt * 16 + quad * 4 + r;
                Pw[row * 40 + lr]      = f2bf(p0);
                Pw[row * 40 + 16 + lr] = f2bf(p1);
            }
#pragma unroll
            for (int msk = 1; msk <= 8; msk <<= 1)
#pragma unroll
                for (int r = 0; r < 4; ++r) ps[r] += __shfl_xor(ps[r], msk, 64);
#pragma unroll
            for (int r = 0; r < 4; ++r) l_r[mt][r] = l_r[mt][r] * al[r] + ps[r];
        }
        // ---- O += P . V  (V^T fragments straight from global/L2) ----
        s16x8 pa[4], vb[4];
#pragma unroll
        for (int mt = 0; mt < 4; ++mt)
            pa[mt] = *(const s16x8*)(Pw + (mt * 16 + lr) * 40 + quad * 8);
#pragma unroll
        for (int nt = 0; nt < 4; ++nt)
            vb[nt] = *(const s16x8*)(Vh + (size_t)(nt * 16 + lr) * KL + j0 + w * 32 + quad * 8);
#pragma unroll
        for (int mt = 0; mt < 4; ++mt)
#pragma unroll
            for (int nt = 0; nt < 4; ++nt)
                O[mt][nt] = __builtin_amdgcn_mfma_f32_16x16x32_bf16(
                    pa[mt], vb[nt], O[mt][nt], 0, 0, 0);
    }

    // ---- merge the 4 per-wave partials ----
    __syncthreads();
    if (lr == 0) {
#pragma unroll
        for (int mt = 0; mt < 4; ++mt)
#pragma unroll
            for (int r = 0; r < 4; ++r) {
                int row = mt * 16 + quad * 4 + r;
                m_s[w * 64 + row] = m_r[mt][r];
                l_s[w * 64 + row] = l_r[mt][r];
            }
    }
    __syncthreads();
    float fw[4][4];
#pragma unroll
    for (int mt = 0; mt < 4; ++mt)
#pragma unroll
        for (int r = 0; r < 4; ++r) {
            int row = mt * 16 + quad * 4 + r;
            float M = fmaxf(fmaxf(m_s[row], m_s[64 + row]),
                            fmaxf(m_s[128 + row], m_s[192 + row]));
            fw[mt][r] = __expf(m_r[mt][r] - M);
        }
    for (int pass = 0; pass < 4; ++pass) {
        if (w == pass) {
#pragma unroll
            for (int mt = 0; mt < 4; ++mt)
#pragma unroll
                for (int nt = 0; nt < 4; ++nt) {
                    int col = nt * 16 + lr;
#pragma unroll
                    for (int r = 0; r < 4; ++r) {
                        int row = mt * 16 + quad * 4 + r;
                        float v = O[mt][nt][r] * fw[mt][r];
                        if (pass == 0) Oacc[row * 66 + col] = v;
                        else           Oacc[row * 66 + col] += v;
                    }
                }
        }
        __syncthreads();
    }
    {
        int row = t >> 2, dg = (t & 3) * 16;
        float M = fmaxf(fmaxf(m_s[row], m_s[64 + row]),
                        fmaxf(m_s[128 + row], m_s[192 + row]));
        float L = 0.0f;
#pragma unroll
        for (int wv = 0; wv < 4; ++wv)
            L += __expf(m_s[wv * 64 + row] - M) * l_s[wv * 64 + row];
        float rL = 1.0f / L;
        int i = i0 + row;
        u16* op = av + (size_t)(i * 2 + b) * DM + n * 64 + dg;
#pragma unroll
        for (int c = 0; c < 16; ++c) op[c] = f2bf(Oacc[row * 66 + dg + c] * rL);
    }
}

// ---------------- fused residual + LayerNorm ----------------
__global__ __launch_bounds__(256) void ln_fused(
    const float* __restrict__ x1, const float* __restrict__ x2,
    const float* __restrict__ gw, const float* __restrict__ bw,
    float* __restrict__ outf, u16* __restrict__ outb, int mode) {
    const int row = blockIdx.x, t = threadIdx.x, lane = t & 63, wv = t >> 6;
    __shared__ float red[8];
    float x[4];
    float s = 0.0f, s2 = 0.0f;
#pragma unroll
    for (int r = 0; r < 4; ++r) {
        int c = t + r * 256;
        float v = x1[(size_t)row * DM + c] + x2[(size_t)row * DM + c];
        x[r] = v;
        s += v;
        s2 += v * v;
    }
#pragma unroll
    for (int o = 32; o; o >>= 1) {
        s  += __shfl_xor(s, o, 64);
        s2 += __shfl_xor(s2, o, 64);
    }
    if (lane == 0) { red[wv] = s; red[4 + wv] = s2; }
    __syncthreads();
    s  = red[0] + red[1] + red[2] + red[3];
    s2 = red[4] + red[5] + red[6] + red[7];
    float mean = s * (1.0f / DM);
    float var  = s2 * (1.0f / DM) - mean * mean;
    float rstd = rsqrtf(var + 1e-5f);
#pragma unroll
    for (int r = 0; r < 4; ++r) {
        int c = t + r * 256;
        float y = gw[c] * (x[r] - mean) * rstd + bw[c];
        size_t idx = (size_t)row * DM + c;
        if (mode & 1) outf[idx] = y;
        if (mode & 2) outb[idx] = f2bf(y);
    }
}

extern "C" void kernel_launch(void* const* d_in, const int* in_sizes, int n_in,
                              void* d_out, int out_size, void* d_ws, size_t ws_size,
                              hipStream_t stream) {
    const float* w        = (const float*)d_in[0];
    const float* mems     = (const float*)d_in[1];
    const float* r_emb    = (const float*)d_in[2];
    const float* r_w_bias = (const float*)d_in[3];
    const float* r_bias   = (const float*)d_in[4];
    const float* qkv_w    = (const float*)d_in[5];
    const float* o_w      = (const float*)d_in[6];
    const float* ln1_g    = (const float*)d_in[7];
    const float* ln1_b    = (const float*)d_in[8];
    const float* ff_w1    = (const float*)d_in[9];
    const float* ff_b1    = (const float*)d_in[10];
    const float* ff_w2    = (const float*)d_in[11];
    const float* ff_b2    = (const float*)d_in[12];
    const float* ln2_g    = (const float*)d_in[13];
    const float* ln2_b    = (const float*)d_in[14];
    float* out = (float*)d_out;

    char* ws = (char*)d_ws;
    size_t off = 0;
    auto alloc = [&](size_t bytes) {
        size_t o = off;
        off += (bytes + 255) & ~(size_t)255;
        return o;
    };
    u16* cat_bf   = (u16*)(ws + alloc((size_t)KL * BATCH * DM * 2));      // b-major
    u16* qkvw_bf  = (u16*)(ws + alloc((size_t)3 * NH * DH * DM * 2));
    u16* ow_bf    = (u16*)(ws + alloc((size_t)DM * NH * DH * 2));
    u16* w1_bf    = (u16*)(ws + alloc((size_t)DI * DM * 2));
    u16* w2_bf    = (u16*)(ws + alloc((size_t)DM * DI * 2));
    u16* r_bf     = (u16*)(ws + alloc((size_t)KL * DM * 2));
    float* rb2    = (float*)(ws + alloc((size_t)NH * KL * 4));
    u16* Wqk_bf   = (u16*)(ws + alloc((size_t)KL * BATCH * 2048 * 2));    // Q|K
    u16* Vt_bf    = (u16*)(ws + alloc((size_t)BATCH * NH * DH * KL * 2)); // V^T
    u16* av_bf    = (u16*)(ws + alloc((size_t)QL * BATCH * DM * 2));
    float* ao_f   = (float*)(ws + alloc((size_t)QL * BATCH * DM * 4));
    float* h_f    = (float*)(ws + alloc((size_t)QL * BATCH * DM * 4));
    u16* h_bf     = (u16*)(ws + alloc((size_t)QL * BATCH * DM * 2));
    u16* inner_bf = (u16*)(ws + alloc((size_t)QL * BATCH * DI * 2));
    float* ffo_f  = (float*)(ws + alloc((size_t)QL * BATCH * DM * 4));
    (void)ws_size; (void)in_sizes; (void)n_in; (void)out_size;

    // 1) conversions + rel-bias prep
    cvt_cat<<<4096, 256, 0, stream>>>(mems, w, cat_bf);
    cvt4<<<3072, 256, 0, stream>>>(qkv_w, qkvw_bf, 3 * NH * DH * DM / 4);
    cvt4<<<1024, 256, 0, stream>>>(o_w, ow_bf, DM * NH * DH / 4);
    cvt4<<<4096, 256, 0, stream>>>(ff_w1, w1_bf, DI * DM / 4);
    cvt4<<<4096, 256, 0, stream>>>(ff_w2, w2_bf, DM * DI / 4);
    cvt4<<<2048, 256, 0, stream>>>(r_emb, r_bf, KL * DM / 4);
    rb2_prep<<<(NH * KL + 255) / 256, 256, 0, stream>>>(r_emb, r_w_bias, r_bias, rb2);

    // 2) QKV projection with V-split epilogue
    gemm_s<128, 1 | 8><<<dim3(3072 / 128, (KL * BATCH) / 128), 256, 0, stream>>>(
        cat_bf, qkvw_bf, nullptr, Wqk_bf, Vt_bf, nullptr, KL * BATCH, 2048, DM);

    // 3) flash attention (XCD-local swizzle)
    flash_attn<<<512, 256, 0, stream>>>(Wqk_bf, Vt_bf, r_bf, r_w_bias, rb2, av_bf);

    // 4) output projection (BN=64 so grid=256 blocks)
    gemm_s<64, 0><<<dim3(DM / 64, (QL * BATCH) / 128), 256, 0, stream>>>(
        av_bf, ow_bf, ao_f, nullptr, nullptr, nullptr, QL * BATCH, DM, DM);

    // 5) h = LN(w + attn_out)
    ln_fused<<<QL * BATCH, 256, 0, stream>>>(w, ao_f, ln1_g, ln1_b, h_f, h_bf, 3);

    // 6) inner = relu(h * ff_w1^T + b1)
    gemm_s<128, 1 | 2 | 4><<<dim3(DI / 128, (QL * BATCH) / 128), 256, 0, stream>>>(
        h_bf, w1_bf, nullptr, inner_bf, nullptr, ff_b1, QL * BATCH, DI, DM);

    // 7) ff_out = inner * ff_w2^T + b2 (BN=64 so grid=256 blocks)
    gemm_s<64, 2><<<dim3(DM / 64, (QL * BATCH) / 128), 256, 0, stream>>>(
        inner_bf, w2_bf, ffo_f, nullptr, nullptr, ff_b2, QL * BATCH, DM, DI);

    // 8) out = LN(h + ff_out)
    ln_fused<<<QL * BATCH, 256, 0, stream>>>(h_f, ffo_f, ln2_g, ln2_b, out, nullptr, 1);
}

// Round 4
// 561.935 us; speedup vs baseline: 1.3645x; 1.3645x over previous
//
#include <hip/hip_runtime.h>
#include <math.h>

#define DM    1024
#define NH    16
#define DH    64
#define DI    4096
#define QL    1024
#define MLN   1024
#define BATCH 2
#define KL    2048   // QL + MLN

typedef unsigned short u16;
typedef short s16x8 __attribute__((ext_vector_type(8)));
typedef float f32x4 __attribute__((ext_vector_type(4)));

__device__ __forceinline__ u16 f2bf(float f) {
    union { float f; unsigned u; } v; v.f = f;
    unsigned u = v.u;
    unsigned r = (u + 0x7FFFu + ((u >> 16) & 1u)) >> 16;
    return (u16)r;
}
__device__ __forceinline__ float bf2f(u16 h) {
    union { unsigned u; float f; } v; v.u = ((unsigned)h) << 16;
    return v.f;
}

__device__ __forceinline__ void gl2lds16(const void* g, void* l) {
    __builtin_amdgcn_global_load_lds(
        (const __attribute__((address_space(1))) void*)g,
        (__attribute__((address_space(3))) void*)l, 16, 0, 0);
}

// ---------------- vectorized fp32 -> bf16 ----------------
__global__ __launch_bounds__(256) void cvt4(const float* __restrict__ x,
                                            u16* __restrict__ y, int n4) {
    int i = blockIdx.x * 256 + threadIdx.x;
    int stride = gridDim.x * 256;
    for (; i < n4; i += stride) {
        float4 v = ((const float4*)x)[i];
        ushort4 o = {f2bf(v.x), f2bf(v.y), f2bf(v.z), f2bf(v.w)};
        ((ushort4*)y)[i] = o;
    }
}

// cat in batch-major layout: cat[b][kpos][:] from mems[k][b][:] / w[i][b][:]
__global__ __launch_bounds__(256) void cvt_cat(const float* __restrict__ mems,
                                               const float* __restrict__ w,
                                               u16* __restrict__ cat) {
    int id = blockIdx.x * 256 + threadIdx.x;     // 4096 rows * 256 chunks
    int c4 = (id & 255) * 4;
    int row = id >> 8;
    int b = row >> 11, kpos = row & 2047;
    const float* src = (kpos < QL)
        ? mems + ((size_t)kpos * BATCH + b) * DM + c4
        : w + ((size_t)(kpos - QL) * BATCH + b) * DM + c4;
    float4 v = *(const float4*)src;
    ushort4 o = {f2bf(v.x), f2bf(v.y), f2bf(v.z), f2bf(v.w)};
    *(ushort4*)(cat + (size_t)row * DM + c4) = o;
}

// rb2[n][jj] = 0.125*(r_bias[jj,n] - r_w_bias[n,:].dot(r_emb[jj,n,:]))
__global__ __launch_bounds__(256) void rb2_prep(const float* __restrict__ r_emb,
                                                const float* __restrict__ r_w_bias,
                                                const float* __restrict__ r_bias,
                                                float* __restrict__ rb2) {
    int id = blockIdx.x * 256 + threadIdx.x;
    if (id >= NH * KL) return;
    int n = id >> 11, jj = id & (KL - 1);
    float dot = 0.0f;
#pragma unroll 8
    for (int d = 0; d < 64; ++d)
        dot += r_w_bias[n * 64 + d] * r_emb[(size_t)jj * (NH * DH) + n * 64 + d];
    rb2[n * KL + jj] = 0.125f * (r_bias[jj * NH + n] - dot);
}

// ---------------- staged GEMM: C[M,*] = A[M,K] * B[*,K]^T ----------------
// BM=128, BK=32. FLAGS: 1=bf16 out, 2=bias, 4=relu, 8=V-split (QKV epilogue).
template <int BN, int FLAGS>
__global__ __launch_bounds__(256) void gemm_s(const u16* __restrict__ A,
                                              const u16* __restrict__ B,
                                              float* __restrict__ Cf,
                                              u16* __restrict__ Cb,
                                              u16* __restrict__ Vt_out,
                                              const float* __restrict__ bias,
                                              int M, int N_out, int K) {
    constexpr int WN = BN / 2;       // per-wave n extent
    constexpr int TN = WN / 16;      // 4 or 2
    __shared__ u16 As[128 * 32];
    __shared__ u16 Bs[BN * 32];

    const int t = threadIdx.x;
    const int lane = t & 63, wid = t >> 6;
    const int wm = wid >> 1, wn = wid & 1;
    const int lr = lane & 15, quad = lane >> 4;
    const int m_blk = blockIdx.y * 128;
    const int n_blk = blockIdx.x * BN;
    const int srow = t >> 2;             // 0..63 staging row
    const int skc  = (t & 3) * 8;        // staging k-chunk (elements)

    f32x4 acc[4][TN];
#pragma unroll
    for (int i = 0; i < 4; ++i)
#pragma unroll
        for (int j = 0; j < TN; ++j) acc[i][j] = (f32x4)0.0f;

    for (int k0 = 0; k0 < K; k0 += 32) {
        __syncthreads();
        gl2lds16(A + (size_t)(m_blk + srow) * K + k0 + skc, As + wid * 512);
        gl2lds16(A + (size_t)(m_blk + 64 + srow) * K + k0 + skc, As + 2048 + wid * 512);
        gl2lds16(B + (size_t)(n_blk + srow) * K + k0 + skc, Bs + wid * 512);
        if (BN == 128)
            gl2lds16(B + (size_t)(n_blk + 64 + srow) * K + k0 + skc, Bs + 2048 + wid * 512);
        __syncthreads();

        s16x8 a[4], b[TN];
#pragma unroll
        for (int i = 0; i < 4; ++i)
            a[i] = *(const s16x8*)(As + (wm * 64 + i * 16 + lr) * 32 + quad * 8);
#pragma unroll
        for (int j = 0; j < TN; ++j)
            b[j] = *(const s16x8*)(Bs + (wn * WN + j * 16 + lr) * 32 + quad * 8);
#pragma unroll
        for (int i = 0; i < 4; ++i)
#pragma unroll
            for (int j = 0; j < TN; ++j)
                acc[i][j] = __builtin_amdgcn_mfma_f32_16x16x32_bf16(
                    a[i], b[j], acc[i][j], 0, 0, 0);
    }

#pragma unroll
    for (int i = 0; i < 4; ++i) {
#pragma unroll
        for (int j = 0; j < TN; ++j) {
            int row0 = m_blk + wm * 64 + i * 16 + quad * 4;
            int col  = n_blk + wn * WN + j * 16 + lr;
            if ((FLAGS & 8) && col >= 2048) {
                // V part: pre-transposed write, 4 consecutive kpos in one store
                int d = col & 63, n = (col >> 6) & 15;
                int b_ = row0 >> 11, kpos = row0 & 2047;
                ushort4 o = {f2bf(acc[i][j][0]), f2bf(acc[i][j][1]),
                             f2bf(acc[i][j][2]), f2bf(acc[i][j][3])};
                *(ushort4*)(Vt_out + ((size_t)((b_ * 16 + n) * 64 + d)) * KL + kpos) = o;
            } else {
                float bv = (FLAGS & 2) ? bias[col] : 0.0f;
#pragma unroll
                for (int r = 0; r < 4; ++r) {
                    float v = acc[i][j][r] + bv;
                    if (FLAGS & 4) v = fmaxf(v, 0.0f);
                    size_t idx = (size_t)(row0 + r) * N_out + col;
                    if (FLAGS & 1) Cb[idx] = f2bf(v);
                    else           Cf[idx] = v;
                }
            }
        }
    }
}

// ---------------- flash attention, XCD-local, V^T from global ----------------
// 1-D grid 512: bn = idx%32 (same-head blocks share an XCD's L2),
// i0 = (idx/32)*64. Wqk: [b*2048+kpos][2048] (Q cols 0..1023, K cols 1024..2047).
// Vt: [ (b*16+n)*64 + d ][2048] pre-transposed V.
// NOTE: __launch_bounds__(256,2) NOT (256,3) — min-waves 3 caps the unified
// VGPR+AGPR budget at ~170 and forces scratch spills (R3: 246 MB WRITE_SIZE).
__global__ __launch_bounds__(256, 2) void flash_attn(
    const u16* __restrict__ Wqk, const u16* __restrict__ Vt_g,
    const u16* __restrict__ r_bf, const float* __restrict__ r_w_bias,
    const float* __restrict__ rb2, u16* __restrict__ av) {
    const int bn = blockIdx.x & 31;
    const int i0 = (blockIdx.x >> 5) * 64;
    const int b = bn >> 4, n = bn & 15;
    const int t = threadIdx.x;
    const int lane = t & 63, w = t >> 6;
    const int lr = lane & 15, quad = lane >> 4;

    __shared__ char smem[47616];
    u16* Bt = (u16*)smem;                       // [64][196] shifted-bias tile
    u16* Pw = (u16*)(smem + 25088) + w * 2560;  // [64][40] probs, per wave
    float* m_s = (float*)(smem + 45568);        // [4][64]
    float* l_s = m_s + 256;                     // [4][64]
    float* Oacc = (float*)smem;                 // [64][66] overlay (final merge)

    const u16* Vh = Vt_g + (size_t)bn * 64 * KL;

    // qw = bf16(0.125*(q + r_w_bias))
    s16x8 qw[4][2];
#pragma unroll
    for (int mt = 0; mt < 4; ++mt)
#pragma unroll
        for (int ks = 0; ks < 2; ++ks) {
            int i = i0 + mt * 16 + lr;
            const u16* qp = Wqk + (size_t)(b * KL + QL + i) * 2048 + n * 64 + ks * 32 + quad * 8;
            s16x8 qv = *(const s16x8*)qp;
            s16x8 o;
#pragma unroll
            for (int k = 0; k < 8; ++k) {
                float f = bf2f((u16)qv[k]) + r_w_bias[n * 64 + ks * 32 + quad * 8 + k];
                o[k] = (short)f2bf(f * 0.125f);
            }
            qw[mt][ks] = o;
        }

    f32x4 O[4][4];
    float m_r[4][4], l_r[4][4];
#pragma unroll
    for (int mt = 0; mt < 4; ++mt)
#pragma unroll
        for (int x = 0; x < 4; ++x) {
            O[mt][x] = (f32x4)0.0f;
            m_r[mt][x] = -INFINITY;
            l_r[mt][x] = 0.0f;
        }

    const int jend = i0 + 64 + MLN;
    for (int j0 = 0; j0 < jend; j0 += 128) {
        __syncthreads();   // prior iter's Bt reads complete

        // ---- Bt tile: Bt[row][col] = qw . r[jjbase+col] (+rb2) ----
        const int jjbase = j0 + 960 - i0;   // jjloc = colj + 63 - row
        {
            f32x4 bacc[4][3];
#pragma unroll
            for (int mt = 0; mt < 4; ++mt)
#pragma unroll
                for (int c = 0; c < 3; ++c) bacc[mt][c] = (f32x4)0.0f;
#pragma unroll
            for (int ks = 0; ks < 2; ++ks) {
                s16x8 rf[3];
#pragma unroll
                for (int c = 0; c < 3; ++c) {
                    int jj = jjbase + (w * 3 + c) * 16 + lr;
                    jj = jj < 0 ? 0 : (jj > KL - 1 ? KL - 1 : jj);
                    rf[c] = *(const s16x8*)(r_bf + (size_t)jj * DM + n * 64 + ks * 32 + quad * 8);
                }
#pragma unroll
                for (int mt = 0; mt < 4; ++mt)
#pragma unroll
                    for (int c = 0; c < 3; ++c)
                        bacc[mt][c] = __builtin_amdgcn_mfma_f32_16x16x32_bf16(
                            qw[mt][ks], rf[c], bacc[mt][c], 0, 0, 0);
            }
            float rbv[3];
#pragma unroll
            for (int c = 0; c < 3; ++c) {
                int jj = jjbase + (w * 3 + c) * 16 + lr;
                rbv[c] = (jj >= 0 && jj < KL) ? rb2[n * KL + jj] : 0.0f;
            }
#pragma unroll
            for (int mt = 0; mt < 4; ++mt)
#pragma unroll
                for (int c = 0; c < 3; ++c) {
                    int col = (w * 3 + c) * 16 + lr;
#pragma unroll
                    for (int r = 0; r < 4; ++r) {
                        int row = mt * 16 + quad * 4 + r;
                        Bt[row * 196 + col] = f2bf(bacc[mt][c][r] + rbv[c]);
                    }
                }
        }
        __syncthreads();

        // ---- S = qw . K^T for this wave's 32 cols ----
        f32x4 sacc[4][2];
#pragma unroll
        for (int mt = 0; mt < 4; ++mt)
#pragma unroll
            for (int nt = 0; nt < 2; ++nt) sacc[mt][nt] = (f32x4)0.0f;
#pragma unroll
        for (int ks = 0; ks < 2; ++ks) {
            s16x8 kf[2];
#pragma unroll
            for (int nt = 0; nt < 2; ++nt) {
                int j = j0 + w * 32 + nt * 16 + lr;
                kf[nt] = *(const s16x8*)(Wqk + (size_t)(b * KL + j) * 2048 + 1024 + n * 64 + ks * 32 + quad * 8);
            }
#pragma unroll
            for (int mt = 0; mt < 4; ++mt)
#pragma unroll
                for (int nt = 0; nt < 2; ++nt)
                    sacc[mt][nt] = __builtin_amdgcn_mfma_f32_16x16x32_bf16(
                        qw[mt][ks], kf[nt], sacc[mt][nt], 0, 0, 0);
        }
        // ---- add shifted bias, mask ----
#pragma unroll
        for (int mt = 0; mt < 4; ++mt)
#pragma unroll
            for (int nt = 0; nt < 2; ++nt) {
                int colj = w * 32 + nt * 16 + lr;
                int j = j0 + colj;
#pragma unroll
                for (int r = 0; r < 4; ++r) {
                    int row = mt * 16 + quad * 4 + r;
                    int i = i0 + row;
                    int jjloc = colj + 63 - row;
                    float v = sacc[mt][nt][r] + bf2f(Bt[row * 196 + jjloc]);
                    sacc[mt][nt][r] = (j <= i + MLN) ? v : -INFINITY;
                }
            }
        // ---- online softmax update ----
#pragma unroll
        for (int mt = 0; mt < 4; ++mt) {
            float rmax[4], al[4], ps[4];
#pragma unroll
            for (int r = 0; r < 4; ++r) rmax[r] = fmaxf(sacc[mt][0][r], sacc[mt][1][r]);
#pragma unroll
            for (int msk = 1; msk <= 8; msk <<= 1)
#pragma unroll
                for (int r = 0; r < 4; ++r)
                    rmax[r] = fmaxf(rmax[r], __shfl_xor(rmax[r], msk, 64));
#pragma unroll
            for (int r = 0; r < 4; ++r) {
                float mo = m_r[mt][r];
                float mn = fmaxf(mo, rmax[r]);
                float a = __expf(mo - mn);
                m_r[mt][r] = mn; al[r] = a;
#pragma unroll
                for (int nt = 0; nt < 4; ++nt) O[mt][nt][r] *= a;
                float p0 = __expf(sacc[mt][0][r] - mn);
                float p1 = __expf(sacc[mt][1][r] - mn);
                ps[r] = p0 + p1;
                int row = mt * 16 + quad * 4 + r;
                Pw[row * 40 + lr]      = f2bf(p0);
                Pw[row * 40 + 16 + lr] = f2bf(p1);
            }
#pragma unroll
            for (int msk = 1; msk <= 8; msk <<= 1)
#pragma unroll
                for (int r = 0; r < 4; ++r) ps[r] += __shfl_xor(ps[r], msk, 64);
#pragma unroll
            for (int r = 0; r < 4; ++r) l_r[mt][r] = l_r[mt][r] * al[r] + ps[r];
        }
        // ---- O += P . V  (V^T fragments straight from global/L2) ----
        s16x8 pa[4], vb[4];
#pragma unroll
        for (int mt = 0; mt < 4; ++mt)
            pa[mt] = *(const s16x8*)(Pw + (mt * 16 + lr) * 40 + quad * 8);
#pragma unroll
        for (int nt = 0; nt < 4; ++nt)
            vb[nt] = *(const s16x8*)(Vh + (size_t)(nt * 16 + lr) * KL + j0 + w * 32 + quad * 8);
#pragma unroll
        for (int mt = 0; mt < 4; ++mt)
#pragma unroll
            for (int nt = 0; nt < 4; ++nt)
                O[mt][nt] = __builtin_amdgcn_mfma_f32_16x16x32_bf16(
                    pa[mt], vb[nt], O[mt][nt], 0, 0, 0);
    }

    // ---- merge the 4 per-wave partials ----
    __syncthreads();
    if (lr == 0) {
#pragma unroll
        for (int mt = 0; mt < 4; ++mt)
#pragma unroll
            for (int r = 0; r < 4; ++r) {
                int row = mt * 16 + quad * 4 + r;
                m_s[w * 64 + row] = m_r[mt][r];
                l_s[w * 64 + row] = l_r[mt][r];
            }
    }
    __syncthreads();
    float fw[4][4];
#pragma unroll
    for (int mt = 0; mt < 4; ++mt)
#pragma unroll
        for (int r = 0; r < 4; ++r) {
            int row = mt * 16 + quad * 4 + r;
            float M = fmaxf(fmaxf(m_s[row], m_s[64 + row]),
                            fmaxf(m_s[128 + row], m_s[192 + row]));
            fw[mt][r] = __expf(m_r[mt][r] - M);
        }
    for (int pass = 0; pass < 4; ++pass) {
        if (w == pass) {
#pragma unroll
            for (int mt = 0; mt < 4; ++mt)
#pragma unroll
                for (int nt = 0; nt < 4; ++nt) {
                    int col = nt * 16 + lr;
#pragma unroll
                    for (int r = 0; r < 4; ++r) {
                        int row = mt * 16 + quad * 4 + r;
                        float v = O[mt][nt][r] * fw[mt][r];
                        if (pass == 0) Oacc[row * 66 + col] = v;
                        else           Oacc[row * 66 + col] += v;
                    }
                }
        }
        __syncthreads();
    }
    {
        int row = t >> 2, dg = (t & 3) * 16;
        float M = fmaxf(fmaxf(m_s[row], m_s[64 + row]),
                        fmaxf(m_s[128 + row], m_s[192 + row]));
        float L = 0.0f;
#pragma unroll
        for (int wv = 0; wv < 4; ++wv)
            L += __expf(m_s[wv * 64 + row] - M) * l_s[wv * 64 + row];
        float rL = 1.0f / L;
        int i = i0 + row;
        u16* op = av + (size_t)(i * 2 + b) * DM + n * 64 + dg;
#pragma unroll
        for (int c = 0; c < 16; ++c) op[c] = f2bf(Oacc[row * 66 + dg + c] * rL);
    }
}

// ---------------- fused residual + LayerNorm ----------------
__global__ __launch_bounds__(256) void ln_fused(
    const float* __restrict__ x1, const float* __restrict__ x2,
    const float* __restrict__ gw, const float* __restrict__ bw,
    float* __restrict__ outf, u16* __restrict__ outb, int mode) {
    const int row = blockIdx.x, t = threadIdx.x, lane = t & 63, wv = t >> 6;
    __shared__ float red[8];
    float x[4];
    float s = 0.0f, s2 = 0.0f;
#pragma unroll
    for (int r = 0; r < 4; ++r) {
        int c = t + r * 256;
        float v = x1[(size_t)row * DM + c] + x2[(size_t)row * DM + c];
        x[r] = v;
        s += v;
        s2 += v * v;
    }
#pragma unroll
    for (int o = 32; o; o >>= 1) {
        s  += __shfl_xor(s, o, 64);
        s2 += __shfl_xor(s2, o, 64);
    }
    if (lane == 0) { red[wv] = s; red[4 + wv] = s2; }
    __syncthreads();
    s  = red[0] + red[1] + red[2] + red[3];
    s2 = red[4] + red[5] + red[6] + red[7];
    float mean = s * (1.0f / DM);
    float var  = s2 * (1.0f / DM) - mean * mean;
    float rstd = rsqrtf(var + 1e-5f);
#pragma unroll
    for (int r = 0; r < 4; ++r) {
        int c = t + r * 256;
        float y = gw[c] * (x[r] - mean) * rstd + bw[c];
        size_t idx = (size_t)row * DM + c;
        if (mode & 1) outf[idx] = y;
        if (mode & 2) outb[idx] = f2bf(y);
    }
}

extern "C" void kernel_launch(void* const* d_in, const int* in_sizes, int n_in,
                              void* d_out, int out_size, void* d_ws, size_t ws_size,
                              hipStream_t stream) {
    const float* w        = (const float*)d_in[0];
    const float* mems     = (const float*)d_in[1];
    const float* r_emb    = (const float*)d_in[2];
    const float* r_w_bias = (const float*)d_in[3];
    const float* r_bias   = (const float*)d_in[4];
    const float* qkv_w    = (const float*)d_in[5];
    const float* o_w      = (const float*)d_in[6];
    const float* ln1_g    = (const float*)d_in[7];
    const float* ln1_b    = (const float*)d_in[8];
    const float* ff_w1    = (const float*)d_in[9];
    const float* ff_b1    = (const float*)d_in[10];
    const float* ff_w2    = (const float*)d_in[11];
    const float* ff_b2    = (const float*)d_in[12];
    const float* ln2_g    = (const float*)d_in[13];
    const float* ln2_b    = (const float*)d_in[14];
    float* out = (float*)d_out;

    char* ws = (char*)d_ws;
    size_t off = 0;
    auto alloc = [&](size_t bytes) {
        size_t o = off;
        off += (bytes + 255) & ~(size_t)255;
        return o;
    };
    u16* cat_bf   = (u16*)(ws + alloc((size_t)KL * BATCH * DM * 2));      // b-major
    u16* qkvw_bf  = (u16*)(ws + alloc((size_t)3 * NH * DH * DM * 2));
    u16* ow_bf    = (u16*)(ws + alloc((size_t)DM * NH * DH * 2));
    u16* w1_bf    = (u16*)(ws + alloc((size_t)DI * DM * 2));
    u16* w2_bf    = (u16*)(ws + alloc((size_t)DM * DI * 2));
    u16* r_bf     = (u16*)(ws + alloc((size_t)KL * DM * 2));
    float* rb2    = (float*)(ws + alloc((size_t)NH * KL * 4));
    u16* Wqk_bf   = (u16*)(ws + alloc((size_t)KL * BATCH * 2048 * 2));    // Q|K
    u16* Vt_bf    = (u16*)(ws + alloc((size_t)BATCH * NH * DH * KL * 2)); // V^T
    u16* av_bf    = (u16*)(ws + alloc((size_t)QL * BATCH * DM * 2));
    float* ao_f   = (float*)(ws + alloc((size_t)QL * BATCH * DM * 4));
    float* h_f    = (float*)(ws + alloc((size_t)QL * BATCH * DM * 4));
    u16* h_bf     = (u16*)(ws + alloc((size_t)QL * BATCH * DM * 2));
    u16* inner_bf = (u16*)(ws + alloc((size_t)QL * BATCH * DI * 2));
    float* ffo_f  = (float*)(ws + alloc((size_t)QL * BATCH * DM * 4));
    (void)ws_size; (void)in_sizes; (void)n_in; (void)out_size;

    // 1) conversions + rel-bias prep
    cvt_cat<<<4096, 256, 0, stream>>>(mems, w, cat_bf);
    cvt4<<<3072, 256, 0, stream>>>(qkv_w, qkvw_bf, 3 * NH * DH * DM / 4);
    cvt4<<<1024, 256, 0, stream>>>(o_w, ow_bf, DM * NH * DH / 4);
    cvt4<<<4096, 256, 0, stream>>>(ff_w1, w1_bf, DI * DM / 4);
    cvt4<<<4096, 256, 0, stream>>>(ff_w2, w2_bf, DM * DI / 4);
    cvt4<<<2048, 256, 0, stream>>>(r_emb, r_bf, KL * DM / 4);
    rb2_prep<<<(NH * KL + 255) / 256, 256, 0, stream>>>(r_emb, r_w_bias, r_bias, rb2);

    // 2) QKV projection with V-split epilogue
    gemm_s<128, 1 | 8><<<dim3(3072 / 128, (KL * BATCH) / 128), 256, 0, stream>>>(
        cat_bf, qkvw_bf, nullptr, Wqk_bf, Vt_bf, nullptr, KL * BATCH, 2048, DM);

    // 3) flash attention (XCD-local swizzle)
    flash_attn<<<512, 256, 0, stream>>>(Wqk_bf, Vt_bf, r_bf, r_w_bias, rb2, av_bf);

    // 4) output projection (BN=64 so grid=256 blocks)
    gemm_s<64, 0><<<dim3(DM / 64, (QL * BATCH) / 128), 256, 0, stream>>>(
        av_bf, ow_bf, ao_f, nullptr, nullptr, nullptr, QL * BATCH, DM, DM);

    // 5) h = LN(w + attn_out)
    ln_fused<<<QL * BATCH, 256, 0, stream>>>(w, ao_f, ln1_g, ln1_b, h_f, h_bf, 3);

    // 6) inner = relu(h * ff_w1^T + b1)
    gemm_s<128, 1 | 2 | 4><<<dim3(DI / 128, (QL * BATCH) / 128), 256, 0, stream>>>(
        h_bf, w1_bf, nullptr, inner_bf, nullptr, ff_b1, QL * BATCH, DI, DM);

    // 7) ff_out = inner * ff_w2^T + b2 (BN=64 so grid=256 blocks)
    gemm_s<64, 2><<<dim3(DM / 64, (QL * BATCH) / 128), 256, 0, stream>>>(
        inner_bf, w2_bf, ffo_f, nullptr, nullptr, ff_b2, QL * BATCH, DM, DI);

    // 8) out = LN(h + ff_out)
    ln_fused<<<QL * BATCH, 256, 0, stream>>>(h_f, ffo_f, ln2_g, ln2_b, out, nullptr, 1);
}

// Round 6
// 519.481 us; speedup vs baseline: 1.4760x; 1.0817x over previous
//
#include <hip/hip_runtime.h>
#include <math.h>

#define DM    1024
#define NH    16
#define DH    64
#define DI    4096
#define QL    1024
#define MLN   1024
#define BATCH 2
#define KL    2048   // QL + MLN

typedef unsigned short u16;
typedef short s16x8 __attribute__((ext_vector_type(8)));
typedef float f32x4 __attribute__((ext_vector_type(4)));

__device__ __forceinline__ u16 f2bf(float f) {
    union { float f; unsigned u; } v; v.f = f;
    unsigned u = v.u;
    unsigned r = (u + 0x7FFFu + ((u >> 16) & 1u)) >> 16;
    return (u16)r;
}
// round-half-up: 2 VALU ops, error <= 2^-9 relative — fine at 2% tolerance
__device__ __forceinline__ u16 f2bf_fast(float f) {
    union { float f; unsigned u; } v; v.f = f;
    return (u16)((v.u + 0x8000u) >> 16);
}
__device__ __forceinline__ float bf2f(u16 h) {
    union { unsigned u; float f; } v; v.u = ((unsigned)h) << 16;
    return v.f;
}

__device__ __forceinline__ void gl2lds16(const void* g, void* l) {
    __builtin_amdgcn_global_load_lds(
        (const __attribute__((address_space(1))) void*)g,
        (__attribute__((address_space(3))) void*)l, 16, 0, 0);
}

// ---------------- vectorized fp32 -> bf16 ----------------
__global__ __launch_bounds__(256) void cvt4(const float* __restrict__ x,
                                            u16* __restrict__ y, int n4) {
    int i = blockIdx.x * 256 + threadIdx.x;
    int stride = gridDim.x * 256;
    for (; i < n4; i += stride) {
        float4 v = ((const float4*)x)[i];
        ushort4 o = {f2bf(v.x), f2bf(v.y), f2bf(v.z), f2bf(v.w)};
        ((ushort4*)y)[i] = o;
    }
}

// cat in batch-major layout: cat[b][kpos][:] from mems[k][b][:] / w[i][b][:]
__global__ __launch_bounds__(256) void cvt_cat(const float* __restrict__ mems,
                                               const float* __restrict__ w,
                                               u16* __restrict__ cat) {
    int id = blockIdx.x * 256 + threadIdx.x;     // 4096 rows * 256 chunks
    int c4 = (id & 255) * 4;
    int row = id >> 8;
    int b = row >> 11, kpos = row & 2047;
    const float* src = (kpos < QL)
        ? mems + ((size_t)kpos * BATCH + b) * DM + c4
        : w + ((size_t)(kpos - QL) * BATCH + b) * DM + c4;
    float4 v = *(const float4*)src;
    ushort4 o = {f2bf(v.x), f2bf(v.y), f2bf(v.z), f2bf(v.w)};
    *(ushort4*)(cat + (size_t)row * DM + c4) = o;
}

// rb2[n][jj] = 0.125*(r_bias[jj,n] - r_w_bias[n,:].dot(r_emb[jj,n,:]))
__global__ __launch_bounds__(256) void rb2_prep(const float* __restrict__ r_emb,
                                                const float* __restrict__ r_w_bias,
                                                const float* __restrict__ r_bias,
                                                float* __restrict__ rb2) {
    int id = blockIdx.x * 256 + threadIdx.x;
    if (id >= NH * KL) return;
    int n = id >> 11, jj = id & (KL - 1);
    float dot = 0.0f;
#pragma unroll 8
    for (int d = 0; d < 64; ++d)
        dot += r_w_bias[n * 64 + d] * r_emb[(size_t)jj * (NH * DH) + n * 64 + d];
    rb2[n * KL + jj] = 0.125f * (r_bias[jj * NH + n] - dot);
}

// ---------------- staged GEMM: C[M,*] = A[M,K] * B[*,K]^T ----------------
// BM=128, BK=32. FLAGS: 1=bf16 out, 2=bias, 4=relu, 8=V-split (QKV epilogue).
template <int BN, int FLAGS>
__global__ __launch_bounds__(256) void gemm_s(const u16* __restrict__ A,
                                              const u16* __restrict__ B,
                                              float* __restrict__ Cf,
                                              u16* __restrict__ Cb,
                                              u16* __restrict__ Vt_out,
                                              const float* __restrict__ bias,
                                              int M, int N_out, int K) {
    constexpr int WN = BN / 2;       // per-wave n extent
    constexpr int TN = WN / 16;      // 4 or 2
    __shared__ u16 As[128 * 32];
    __shared__ u16 Bs[BN * 32];

    const int t = threadIdx.x;
    const int lane = t & 63, wid = t >> 6;
    const int wm = wid >> 1, wn = wid & 1;
    const int lr = lane & 15, quad = lane >> 4;
    const int m_blk = blockIdx.y * 128;
    const int n_blk = blockIdx.x * BN;
    const int srow = t >> 2;             // 0..63 staging row
    const int skc  = (t & 3) * 8;        // staging k-chunk (elements)

    f32x4 acc[4][TN];
#pragma unroll
    for (int i = 0; i < 4; ++i)
#pragma unroll
        for (int j = 0; j < TN; ++j) acc[i][j] = (f32x4)0.0f;

    for (int k0 = 0; k0 < K; k0 += 32) {
        __syncthreads();
        gl2lds16(A + (size_t)(m_blk + srow) * K + k0 + skc, As + wid * 512);
        gl2lds16(A + (size_t)(m_blk + 64 + srow) * K + k0 + skc, As + 2048 + wid * 512);
        gl2lds16(B + (size_t)(n_blk + srow) * K + k0 + skc, Bs + wid * 512);
        if (BN == 128)
            gl2lds16(B + (size_t)(n_blk + 64 + srow) * K + k0 + skc, Bs + 2048 + wid * 512);
        __syncthreads();

        s16x8 a[4], b[TN];
#pragma unroll
        for (int i = 0; i < 4; ++i)
            a[i] = *(const s16x8*)(As + (wm * 64 + i * 16 + lr) * 32 + quad * 8);
#pragma unroll
        for (int j = 0; j < TN; ++j)
            b[j] = *(const s16x8*)(Bs + (wn * WN + j * 16 + lr) * 32 + quad * 8);
#pragma unroll
        for (int i = 0; i < 4; ++i)
#pragma unroll
            for (int j = 0; j < TN; ++j)
                acc[i][j] = __builtin_amdgcn_mfma_f32_16x16x32_bf16(
                    a[i], b[j], acc[i][j], 0, 0, 0);
    }

#pragma unroll
    for (int i = 0; i < 4; ++i) {
#pragma unroll
        for (int j = 0; j < TN; ++j) {
            int row0 = m_blk + wm * 64 + i * 16 + quad * 4;
            int col  = n_blk + wn * WN + j * 16 + lr;
            if ((FLAGS & 8) && col >= 2048) {
                // V part: pre-transposed write, 4 consecutive kpos in one store
                int d = col & 63, n = (col >> 6) & 15;
                int b_ = row0 >> 11, kpos = row0 & 2047;
                ushort4 o = {f2bf(acc[i][j][0]), f2bf(acc[i][j][1]),
                             f2bf(acc[i][j][2]), f2bf(acc[i][j][3])};
                *(ushort4*)(Vt_out + ((size_t)((b_ * 16 + n) * 64 + d)) * KL + kpos) = o;
            } else {
                float bv = (FLAGS & 2) ? bias[col] : 0.0f;
#pragma unroll
                for (int r = 0; r < 4; ++r) {
                    float v = acc[i][j][r] + bv;
                    if (FLAGS & 4) v = fmaxf(v, 0.0f);
                    size_t idx = (size_t)(row0 + r) * N_out + col;
                    if (FLAGS & 1) Cb[idx] = f2bf(v);
                    else           Cf[idx] = v;
                }
            }
        }
    }
}

// ---------------- flash attention: wave-per-16-row strip, barrier-free ----------------
// Grid 512: bn = idx%32 (XCD-local), i0 = (idx/32)*64. Wave w owns Q rows
// i0+w*16 .. +16. All LDS per-wave -> NO __syncthreads anywhere.
// LDS TYPE RULE: BtT/Pw are written AND read as u16 (or ext-vector) — mixing
// a 32-bit packed store with u16 loads lets strict TBAA reorder ds ops (R5 NaN).
__global__ __launch_bounds__(256, 3) void flash_attn(
    const u16* __restrict__ Wqk, const u16* __restrict__ Vt_g,
    const u16* __restrict__ r_bf, const float* __restrict__ r_w_bias,
    const float* __restrict__ rb2, u16* __restrict__ av) {
    const int bn = blockIdx.x & 31;
    const int i0 = (blockIdx.x >> 5) * 64;
    const int b = bn >> 4, n = bn & 15;
    const int t = threadIdx.x;
    const int lane = t & 63, w = t >> 6;
    const int lr = lane & 15, quad = lane >> 4;

    // Per-wave LDS. BtT: transposed bias tile [jjloc 144][rho 16], stride 18
    // (bank stride 9 -> conflict-free). Pw: probs [rho 16][col 128], stride 136.
    __shared__ __align__(16) u16 BtT_all[4 * 144 * 18];   // 20736 B
    __shared__ __align__(16) u16 Pw_all[4 * 16 * 136];    // 17408 B
    u16* BtT = BtT_all + w * (144 * 18);
    u16* Pw  = Pw_all  + w * (16 * 136);

    const u16* Vh = Vt_g + (size_t)bn * 64 * KL;
    const int wrow0 = i0 + w * 16;        // this wave's first Q row

    // qw = bf16(0.125*(q + r_w_bias)) for rows wrow0+lr
    s16x8 qw[2];
#pragma unroll
    for (int ks = 0; ks < 2; ++ks) {
        const u16* qp = Wqk + (size_t)(b * KL + QL + wrow0 + lr) * 2048 + n * 64 + ks * 32 + quad * 8;
        s16x8 qv = *(const s16x8*)qp;
        s16x8 o;
#pragma unroll
        for (int k = 0; k < 8; ++k) {
            float f = bf2f((u16)qv[k]) + r_w_bias[n * 64 + ks * 32 + quad * 8 + k];
            o[k] = (short)f2bf(f * 0.125f);
        }
        qw[ks] = o;
    }

    f32x4 O[4];
    float m_r[4], l_r[4];
#pragma unroll
    for (int x = 0; x < 4; ++x) {
        O[x] = (f32x4)0.0f;
        m_r[x] = -INFINITY;
        l_r[x] = 0.0f;
    }

    const int jend = i0 + 64 + MLN;
    for (int j0 = 0; j0 < jend; j0 += 128) {
        // ---- Bt (transposed): BtT[col][rho] = qw_row . r[jjbase+col] + rb2 ----
        // jj = j0 + colj + 1023 - i  =>  jjloc = colj + 15 - rho
        const int jjbase = j0 + 1008 - i0 - w * 16;
#pragma unroll
        for (int cc = 0; cc < 9; cc += 3) {
            f32x4 bacc[3];
#pragma unroll
            for (int c = 0; c < 3; ++c) bacc[c] = (f32x4)0.0f;
#pragma unroll
            for (int ks = 0; ks < 2; ++ks) {
                s16x8 rf[3];
#pragma unroll
                for (int c = 0; c < 3; ++c) {
                    int jj = jjbase + (cc + c) * 16 + lr;
                    int jjc = jj > KL - 1 ? KL - 1 : jj;   // jj >= 0 always
                    rf[c] = *(const s16x8*)(r_bf + (size_t)jjc * DM + n * 64 + ks * 32 + quad * 8);
                }
#pragma unroll
                for (int c = 0; c < 3; ++c)
                    bacc[c] = __builtin_amdgcn_mfma_f32_16x16x32_bf16(
                        qw[ks], rf[c], bacc[c], 0, 0, 0);
            }
#pragma unroll
            for (int c = 0; c < 3; ++c) {
                int col = (cc + c) * 16 + lr;
                int jj = jjbase + col;
                float rbv = (jj < KL) ? rb2[n * KL + jj] : 0.0f;
                u16* dst = BtT + col * 18 + quad * 4;
                dst[0] = f2bf_fast(bacc[c][0] + rbv);
                dst[1] = f2bf_fast(bacc[c][1] + rbv);
                dst[2] = f2bf_fast(bacc[c][2] + rbv);
                dst[3] = f2bf_fast(bacc[c][3] + rbv);
            }
        }

        // ---- S = qw . K^T : 16 rows x 128 cols ----
        f32x4 sacc[8];
#pragma unroll
        for (int nt = 0; nt < 8; ++nt) sacc[nt] = (f32x4)0.0f;
#pragma unroll
        for (int ks = 0; ks < 2; ++ks) {
#pragma unroll
            for (int nn = 0; nn < 8; nn += 4) {
                s16x8 kf[4];
#pragma unroll
                for (int c = 0; c < 4; ++c) {
                    int j = j0 + (nn + c) * 16 + lr;
                    kf[c] = *(const s16x8*)(Wqk + (size_t)(b * KL + j) * 2048 + 1024 + n * 64 + ks * 32 + quad * 8);
                }
#pragma unroll
                for (int c = 0; c < 4; ++c)
                    sacc[nn + c] = __builtin_amdgcn_mfma_f32_16x16x32_bf16(
                        qw[ks], kf[c], sacc[nn + c], 0, 0, 0);
            }
        }

        // ---- add shifted bias, mask ----
#pragma unroll
        for (int nt = 0; nt < 8; ++nt) {
            int colj = nt * 16 + lr;
            int j = j0 + colj;
#pragma unroll
            for (int r = 0; r < 4; ++r) {
                int rho = quad * 4 + r;
                int i = wrow0 + rho;
                int jjloc = colj + 15 - rho;
                float v = sacc[nt][r] + bf2f(BtT[jjloc * 18 + rho]);
                sacc[nt][r] = (j <= i + MLN) ? v : -INFINITY;
            }
        }

        // ---- online softmax (row-local; reduce over lr lanes only) ----
        float mx[4];
#pragma unroll
        for (int r = 0; r < 4; ++r) {
            mx[r] = sacc[0][r];
#pragma unroll
            for (int nt = 1; nt < 8; ++nt) mx[r] = fmaxf(mx[r], sacc[nt][r]);
        }
#pragma unroll
        for (int msk = 1; msk <= 8; msk <<= 1)
#pragma unroll
            for (int r = 0; r < 4; ++r)
                mx[r] = fmaxf(mx[r], __shfl_xor(mx[r], msk, 64));
        float al[4], mn[4];
#pragma unroll
        for (int r = 0; r < 4; ++r) {
            mn[r] = fmaxf(m_r[r], mx[r]);
            al[r] = __expf(m_r[r] - mn[r]);
            m_r[r] = mn[r];
#pragma unroll
            for (int dt = 0; dt < 4; ++dt) O[dt][r] *= al[r];
        }
        float ps[4] = {0.0f, 0.0f, 0.0f, 0.0f};
#pragma unroll
        for (int nt = 0; nt < 8; ++nt)
#pragma unroll
            for (int r = 0; r < 4; ++r) {
                float p = __expf(sacc[nt][r] - mn[r]);
                ps[r] += p;
                Pw[(quad * 4 + r) * 136 + nt * 16 + lr] = f2bf_fast(p);
            }
#pragma unroll
        for (int msk = 1; msk <= 8; msk <<= 1)
#pragma unroll
            for (int r = 0; r < 4; ++r) ps[r] += __shfl_xor(ps[r], msk, 64);
#pragma unroll
        for (int r = 0; r < 4; ++r) l_r[r] = l_r[r] * al[r] + ps[r];

        // ---- O += P . V (K=128; V^T fragments from global/L2) ----
#pragma unroll
        for (int ks2 = 0; ks2 < 4; ++ks2) {
            s16x8 ap = *(const s16x8*)(Pw + lr * 136 + ks2 * 32 + quad * 8);
            s16x8 vb[4];
#pragma unroll
            for (int dt = 0; dt < 4; ++dt)
                vb[dt] = *(const s16x8*)(Vh + (size_t)(dt * 16 + lr) * KL + j0 + ks2 * 32 + quad * 8);
#pragma unroll
            for (int dt = 0; dt < 4; ++dt)
                O[dt] = __builtin_amdgcn_mfma_f32_16x16x32_bf16(ap, vb[dt], O[dt], 0, 0, 0);
        }
    }

    // ---- epilogue: normalize, write (no cross-wave merge needed) ----
    float rL[4];
#pragma unroll
    for (int r = 0; r < 4; ++r) rL[r] = 1.0f / l_r[r];
#pragma unroll
    for (int dt = 0; dt < 4; ++dt)
#pragma unroll
        for (int r = 0; r < 4; ++r) {
            int i = wrow0 + quad * 4 + r;
            av[(size_t)(i * 2 + b) * DM + n * 64 + dt * 16 + lr] = f2bf(O[dt][r] * rL[r]);
        }
}

// ---------------- fused residual + LayerNorm ----------------
__global__ __launch_bounds__(256) void ln_fused(
    const float* __restrict__ x1, const float* __restrict__ x2,
    const float* __restrict__ gw, const float* __restrict__ bw,
    float* __restrict__ outf, u16* __restrict__ outb, int mode) {
    const int row = blockIdx.x, t = threadIdx.x, lane = t & 63, wv = t >> 6;
    __shared__ float red[8];
    float x[4];
    float s = 0.0f, s2 = 0.0f;
#pragma unroll
    for (int r = 0; r < 4; ++r) {
        int c = t + r * 256;
        float v = x1[(size_t)row * DM + c] + x2[(size_t)row * DM + c];
        x[r] = v;
        s += v;
        s2 += v * v;
    }
#pragma unroll
    for (int o = 32; o; o >>= 1) {
        s  += __shfl_xor(s, o, 64);
        s2 += __shfl_xor(s2, o, 64);
    }
    if (lane == 0) { red[wv] = s; red[4 + wv] = s2; }
    __syncthreads();
    s  = red[0] + red[1] + red[2] + red[3];
    s2 = red[4] + red[5] + red[6] + red[7];
    float mean = s * (1.0f / DM);
    float var  = s2 * (1.0f / DM) - mean * mean;
    float rstd = rsqrtf(var + 1e-5f);
#pragma unroll
    for (int r = 0; r < 4; ++r) {
        int c = t + r * 256;
        float y = gw[c] * (x[r] - mean) * rstd + bw[c];
        size_t idx = (size_t)row * DM + c;
        if (mode & 1) outf[idx] = y;
        if (mode & 2) outb[idx] = f2bf(y);
    }
}

extern "C" void kernel_launch(void* const* d_in, const int* in_sizes, int n_in,
                              void* d_out, int out_size, void* d_ws, size_t ws_size,
                              hipStream_t stream) {
    const float* w        = (const float*)d_in[0];
    const float* mems     = (const float*)d_in[1];
    const float* r_emb    = (const float*)d_in[2];
    const float* r_w_bias = (const float*)d_in[3];
    const float* r_bias   = (const float*)d_in[4];
    const float* qkv_w    = (const float*)d_in[5];
    const float* o_w      = (const float*)d_in[6];
    const float* ln1_g    = (const float*)d_in[7];
    const float* ln1_b    = (const float*)d_in[8];
    const float* ff_w1    = (const float*)d_in[9];
    const float* ff_b1    = (const float*)d_in[10];
    const float* ff_w2    = (const float*)d_in[11];
    const float* ff_b2    = (const float*)d_in[12];
    const float* ln2_g    = (const float*)d_in[13];
    const float* ln2_b    = (const float*)d_in[14];
    float* out = (float*)d_out;

    char* ws = (char*)d_ws;
    size_t off = 0;
    auto alloc = [&](size_t bytes) {
        size_t o = off;
        off += (bytes + 255) & ~(size_t)255;
        return o;
    };
    u16* cat_bf   = (u16*)(ws + alloc((size_t)KL * BATCH * DM * 2));      // b-major
    u16* qkvw_bf  = (u16*)(ws + alloc((size_t)3 * NH * DH * DM * 2));
    u16* ow_bf    = (u16*)(ws + alloc((size_t)DM * NH * DH * 2));
    u16* w1_bf    = (u16*)(ws + alloc((size_t)DI * DM * 2));
    u16* w2_bf    = (u16*)(ws + alloc((size_t)DM * DI * 2));
    u16* r_bf     = (u16*)(ws + alloc((size_t)KL * DM * 2));
    float* rb2    = (float*)(ws + alloc((size_t)NH * KL * 4));
    u16* Wqk_bf   = (u16*)(ws + alloc((size_t)KL * BATCH * 2048 * 2));    // Q|K
    u16* Vt_bf    = (u16*)(ws + alloc((size_t)BATCH * NH * DH * KL * 2)); // V^T
    u16* av_bf    = (u16*)(ws + alloc((size_t)QL * BATCH * DM * 2));
    float* ao_f   = (float*)(ws + alloc((size_t)QL * BATCH * DM * 4));
    float* h_f    = (float*)(ws + alloc((size_t)QL * BATCH * DM * 4));
    u16* h_bf     = (u16*)(ws + alloc((size_t)QL * BATCH * DM * 2));
    u16* inner_bf = (u16*)(ws + alloc((size_t)QL * BATCH * DI * 2));
    float* ffo_f  = (float*)(ws + alloc((size_t)QL * BATCH * DM * 4));
    (void)ws_size; (void)in_sizes; (void)n_in; (void)out_size;

    // 1) conversions + rel-bias prep
    cvt_cat<<<4096, 256, 0, stream>>>(mems, w, cat_bf);
    cvt4<<<3072, 256, 0, stream>>>(qkv_w, qkvw_bf, 3 * NH * DH * DM / 4);
    cvt4<<<1024, 256, 0, stream>>>(o_w, ow_bf, DM * NH * DH / 4);
    cvt4<<<4096, 256, 0, stream>>>(ff_w1, w1_bf, DI * DM / 4);
    cvt4<<<4096, 256, 0, stream>>>(ff_w2, w2_bf, DM * DI / 4);
    cvt4<<<2048, 256, 0, stream>>>(r_emb, r_bf, KL * DM / 4);
    rb2_prep<<<(NH * KL + 255) / 256, 256, 0, stream>>>(r_emb, r_w_bias, r_bias, rb2);

    // 2) QKV projection with V-split epilogue
    gemm_s<128, 1 | 8><<<dim3(3072 / 128, (KL * BATCH) / 128), 256, 0, stream>>>(
        cat_bf, qkvw_bf, nullptr, Wqk_bf, Vt_bf, nullptr, KL * BATCH, 2048, DM);

    // 3) flash attention (barrier-free, XCD-local)
    flash_attn<<<512, 256, 0, stream>>>(Wqk_bf, Vt_bf, r_bf, r_w_bias, rb2, av_bf);

    // 4) output projection (BN=64 so grid=256 blocks)
    gemm_s<64, 0><<<dim3(DM / 64, (QL * BATCH) / 128), 256, 0, stream>>>(
        av_bf, ow_bf, ao_f, nullptr, nullptr, nullptr, QL * BATCH, DM, DM);

    // 5) h = LN(w + attn_out)
    ln_fused<<<QL * BATCH, 256, 0, stream>>>(w, ao_f, ln1_g, ln1_b, h_f, h_bf, 3);

    // 6) inner = relu(h * ff_w1^T + b1)
    gemm_s<128, 1 | 2 | 4><<<dim3(DI / 128, (QL * BATCH) / 128), 256, 0, stream>>>(
        h_bf, w1_bf, nullptr, inner_bf, nullptr, ff_b1, QL * BATCH, DI, DM);

    // 7) ff_out = inner * ff_w2^T + b2 (BN=64 so grid=256 blocks)
    gemm_s<64, 2><<<dim3(DM / 64, (QL * BATCH) / 128), 256, 0, stream>>>(
        inner_bf, w2_bf, ffo_f, nullptr, nullptr, ff_b2, QL * BATCH, DM, DI);

    // 8) out = LN(h + ff_out)
    ln_fused<<<QL * BATCH, 256, 0, stream>>>(h_f, ffo_f, ln2_g, ln2_b, out, nullptr, 1);
}

// Round 7
// 376.441 us; speedup vs baseline: 2.0368x; 1.3800x over previous
//
#include <hip/hip_runtime.h>
#include <math.h>

#define DM    1024
#define NH    16
#define DH    64
#define DI    4096
#define QL    1024
#define MLN   1024
#define BATCH 2
#define KL    2048   // QL + MLN
#define RPAD  2304   // padded jj extent for rh / rb2

typedef unsigned short u16;
typedef short s16x8 __attribute__((ext_vector_type(8)));
typedef float f32x4 __attribute__((ext_vector_type(4)));

__device__ __forceinline__ u16 f2bf(float f) {
    union { float f; unsigned u; } v; v.f = f;
    unsigned u = v.u;
    unsigned r = (u + 0x7FFFu + ((u >> 16) & 1u)) >> 16;
    return (u16)r;
}
__device__ __forceinline__ u16 f2bf_fast(float f) {
    union { float f; unsigned u; } v; v.f = f;
    return (u16)((v.u + 0x8000u) >> 16);
}
__device__ __forceinline__ float bf2f(u16 h) {
    union { unsigned u; float f; } v; v.u = ((unsigned)h) << 16;
    return v.f;
}

__device__ __forceinline__ void gl2lds16(const void* g, void* l) {
    __builtin_amdgcn_global_load_lds(
        (const __attribute__((address_space(1))) void*)g,
        (__attribute__((address_space(3))) void*)l, 16, 0, 0);
}

// ---------------- fused weight fp32->bf16 (one launch) ----------------
__global__ __launch_bounds__(256) void cvt_multi(
    const float* __restrict__ a0, const float* __restrict__ a1,
    const float* __restrict__ a2, const float* __restrict__ a3,
    u16* __restrict__ o0, u16* __restrict__ o1,
    u16* __restrict__ o2, u16* __restrict__ o3) {
    // float4 counts: qkv_w 786432 | o_w 262144 | ff_w1 1048576 | ff_w2 1048576
    int i = blockIdx.x * 256 + threadIdx.x;
    int stride = gridDim.x * 256;
    for (; i < 3145728; i += stride) {
        const float* src; u16* dst; int k;
        if (i < 786432)       { src = a0; dst = o0; k = i; }
        else if (i < 1048576) { src = a1; dst = o1; k = i - 786432; }
        else if (i < 2097152) { src = a2; dst = o2; k = i - 1048576; }
        else                  { src = a3; dst = o3; k = i - 2097152; }
        float4 v = ((const float4*)src)[k];
        ushort4 o = {f2bf(v.x), f2bf(v.y), f2bf(v.z), f2bf(v.w)};
        ((ushort4*)dst)[k] = o;
    }
}

// cat in batch-major layout: cat[b][kpos][:] from mems[k][b][:] / w[i][b][:]
__global__ __launch_bounds__(256) void cvt_cat(const float* __restrict__ mems,
                                               const float* __restrict__ w,
                                               u16* __restrict__ cat) {
    int id = blockIdx.x * 256 + threadIdx.x;
    int c4 = (id & 255) * 4;
    int row = id >> 8;
    int b = row >> 11, kpos = row & 2047;
    const float* src = (kpos < QL)
        ? mems + ((size_t)kpos * BATCH + b) * DM + c4
        : w + ((size_t)(kpos - QL) * BATCH + b) * DM + c4;
    float4 v = *(const float4*)src;
    ushort4 o = {f2bf(v.x), f2bf(v.y), f2bf(v.z), f2bf(v.w)};
    *(ushort4*)(cat + (size_t)row * DM + c4) = o;
}

// rh[n][jj][64d], granule-swizzled: stored granule gs holds logical granule
// gl=(gs-jj)&7 (16B granules). jj>=KL -> zeros. grid dim3(72,16).
__global__ __launch_bounds__(256) void rcvt(const float* __restrict__ r_emb,
                                            u16* __restrict__ rh) {
    int id = blockIdx.x * 256 + threadIdx.x;   // (jj,gs): 2304*8
    int n = blockIdx.y;
    int jj = id >> 3, gs = id & 7;
    s16x8 o;
    if (jj < KL) {
        int gl = (gs - jj) & 7;
        const float* s = r_emb + (size_t)jj * DM + n * 64 + gl * 8;
#pragma unroll
        for (int k = 0; k < 8; ++k) o[k] = (short)f2bf(s[k]);
    } else {
#pragma unroll
        for (int k = 0; k < 8; ++k) o[k] = 0;
    }
    *(s16x8*)(rh + ((size_t)n * RPAD + jj) * 64 + gs * 8) = o;
}

// rb2[n][jj] = 0.125*(r_bias[jj,n] - r_w_bias[n,:].dot(r_emb[jj,n,:])), padded.
// grid dim3(9,16)
__global__ __launch_bounds__(256) void rb2_prep(const float* __restrict__ r_emb,
                                                const float* __restrict__ r_w_bias,
                                                const float* __restrict__ r_bias,
                                                float* __restrict__ rb2) {
    int jj = blockIdx.x * 256 + threadIdx.x;
    int n = blockIdx.y;
    if (jj >= RPAD) return;
    float v = 0.0f;
    if (jj < KL) {
        float dot = 0.0f;
#pragma unroll 8
        for (int d = 0; d < 64; ++d)
            dot += r_w_bias[n * 64 + d] * r_emb[(size_t)jj * DM + n * 64 + d];
        v = 0.125f * (r_bias[jj * NH + n] - dot);
    }
    rb2[n * RPAD + jj] = v;
}

// ---------------- staged GEMM: C[M,*] = A[M,K] * B[*,K]^T ----------------
// FLAGS: 1=bf16 out, 2=bias, 4=relu, 8=QKV split epilogue (Q/Kh/Vt2 layouts)
template <int BN, int FLAGS>
__global__ __launch_bounds__(256) void gemm_s(const u16* __restrict__ A,
                                              const u16* __restrict__ B,
                                              float* __restrict__ Cf,
                                              u16* __restrict__ Cb,
                                              u16* __restrict__ Qo,
                                              u16* __restrict__ Ko,
                                              u16* __restrict__ Vo,
                                              const float* __restrict__ bias,
                                              int M, int N_out, int K) {
    constexpr int WN = BN / 2;
    constexpr int TN = WN / 16;
    __shared__ u16 As[128 * 32];
    __shared__ u16 Bs[BN * 32];

    const int t = threadIdx.x;
    const int lane = t & 63, wid = t >> 6;
    const int wm = wid >> 1, wn = wid & 1;
    const int lr = lane & 15, quad = lane >> 4;
    const int m_blk = blockIdx.y * 128;
    const int n_blk = blockIdx.x * BN;
    const int srow = t >> 2;
    const int skc  = (t & 3) * 8;

    f32x4 acc[4][TN];
#pragma unroll
    for (int i = 0; i < 4; ++i)
#pragma unroll
        for (int j = 0; j < TN; ++j) acc[i][j] = (f32x4)0.0f;

    for (int k0 = 0; k0 < K; k0 += 32) {
        __syncthreads();
        gl2lds16(A + (size_t)(m_blk + srow) * K + k0 + skc, As + wid * 512);
        gl2lds16(A + (size_t)(m_blk + 64 + srow) * K + k0 + skc, As + 2048 + wid * 512);
        gl2lds16(B + (size_t)(n_blk + srow) * K + k0 + skc, Bs + wid * 512);
        if (BN == 128)
            gl2lds16(B + (size_t)(n_blk + 64 + srow) * K + k0 + skc, Bs + 2048 + wid * 512);
        __syncthreads();

        s16x8 a[4], b[TN];
#pragma unroll
        for (int i = 0; i < 4; ++i)
            a[i] = *(const s16x8*)(As + (wm * 64 + i * 16 + lr) * 32 + quad * 8);
#pragma unroll
        for (int j = 0; j < TN; ++j)
            b[j] = *(const s16x8*)(Bs + (wn * WN + j * 16 + lr) * 32 + quad * 8);
#pragma unroll
        for (int i = 0; i < 4; ++i)
#pragma unroll
            for (int j = 0; j < TN; ++j)
                acc[i][j] = __builtin_amdgcn_mfma_f32_16x16x32_bf16(
                    a[i], b[j], acc[i][j], 0, 0, 0);
    }

#pragma unroll
    for (int i = 0; i < 4; ++i) {
#pragma unroll
        for (int j = 0; j < TN; ++j) {
            int row0 = m_blk + wm * 64 + i * 16 + quad * 4;
            int col  = n_blk + wn * WN + j * 16 + lr;
            if (FLAGS & 8) {
                int b_ = row0 >> 11, kpos = row0 & 2047;
                if (col < 1024) {
                    if (kpos >= QL) {
                        u16* q = Qo + ((size_t)(b_ * QL + kpos - QL)) * 1024 + col;
#pragma unroll
                        for (int r = 0; r < 4; ++r) q[r * 1024] = f2bf(acc[i][j][r]);
                    }
                } else if (col < 2048) {
                    int d = col & 63, nh = (col >> 6) & 15;
                    size_t base = ((size_t)((b_ * 16 + nh) * 16 + (kpos >> 7))) * 8192;
#pragma unroll
                    for (int r = 0; r < 4; ++r) {
                        int jl = (kpos & 127) + r;
                        Ko[base + jl * 64 + (((d >> 3) + jl) & 7) * 8 + (d & 7)] =
                            f2bf(acc[i][j][r]);
                    }
                } else {
                    int d = col & 63, nh = (col >> 6) & 15;
                    int jl = kpos & 127;
                    size_t base = ((size_t)((b_ * 16 + nh) * 16 + (kpos >> 7))) * 8192
                                  + d * 128 + (((jl >> 3) + d) & 15) * 8 + (jl & 7);
                    ushort4 o = {f2bf(acc[i][j][0]), f2bf(acc[i][j][1]),
                                 f2bf(acc[i][j][2]), f2bf(acc[i][j][3])};
                    *(ushort4*)(Vo + base) = o;
                }
            } else {
                float bv = (FLAGS & 2) ? bias[col] : 0.0f;
#pragma unroll
                for (int r = 0; r < 4; ++r) {
                    float v = acc[i][j][r] + bv;
                    if (FLAGS & 4) v = fmaxf(v, 0.0f);
                    size_t idx = (size_t)(row0 + r) * N_out + col;
                    if (FLAGS & 1) Cb[idx] = f2bf(v);
                    else           Cf[idx] = v;
                }
            }
        }
    }
}

// ---------------- flash attention: staged tiles + bpermute rel-shift ----------------
// Grid 512: bn = idx%32 (XCD-local), i0 = (idx/32)*64. Wave w owns Q rows
// [wrow0, wrow0+16). K/V/r tiles staged to LDS via contiguous global_load_lds
// (granule-swizzled global layouts so the unpadded LDS image is conflict-light).
// Rel-shift: Bt lives in MFMA C-layout; the shift only permutes lanes within a
// C-row -> ds_bpermute straight into the S accumulator (no BtT LDS).
__global__ __launch_bounds__(256, 2) void flash_attn(
    const u16* __restrict__ Qb, const u16* __restrict__ Kh,
    const u16* __restrict__ Vt2, const u16* __restrict__ rh,
    const float* __restrict__ r_w_bias, const float* __restrict__ rb2,
    u16* __restrict__ av) {
    const int bn = blockIdx.x & 31;
    const int i0 = (blockIdx.x >> 5) * 64;
    const int b = bn >> 4, n = bn & 15;
    const int t = threadIdx.x;
    const int lane = t & 63, w = t >> 6;
    const int lr = lane & 15, quad = lane >> 4;

    __shared__ __align__(16) u16 Ks[128 * 64];       // 16KB  [jloc][d] swizzled
    __shared__ __align__(16) u16 Vs[64 * 128];       // 16KB  [d][jloc] swizzled
    __shared__ __align__(16) u16 Rs[192 * 64];       // 24KB  [row][d] swizzled
    __shared__ __align__(16) u16 Pw_all[4 * 16 * 136];  // 17KB per-wave probs
    u16* Pw = Pw_all + w * (16 * 136);

    const int wrow0 = i0 + w * 16;

    // qw = bf16(0.125*(q + r_w_bias))
    s16x8 qw[2];
#pragma unroll
    for (int ks = 0; ks < 2; ++ks) {
        const u16* qp = Qb + ((size_t)(b * QL + wrow0 + lr)) * 1024 + n * 64 + ks * 32 + quad * 8;
        s16x8 qv = *(const s16x8*)qp;
        s16x8 o;
#pragma unroll
        for (int k = 0; k < 8; ++k) {
            float f = bf2f((u16)qv[k]) + r_w_bias[n * 64 + ks * 32 + quad * 8 + k];
            o[k] = (short)f2bf(f * 0.125f);
        }
        qw[ks] = o;
    }

    f32x4 O[4];
    float m_r[4], l_r[4];
#pragma unroll
    for (int x = 0; x < 4; ++x) {
        O[x] = (f32x4)0.0f;
        m_r[x] = -INFINITY;
        l_r[x] = 0.0f;
    }

    const u16* Kt0 = Kh + (size_t)bn * 16 * 8192;
    const u16* Vt0 = Vt2 + (size_t)bn * 16 * 8192;
    const int jend = i0 + 64 + MLN;

    for (int j0 = 0; j0 < jend; j0 += 128) {
        const int jjbase_blk = j0 + 960 - i0;   // >= 0 always; &7 == 0
        __syncthreads();
        {
            const u16* Ksrc = Kt0 + (size_t)(j0 >> 7) * 8192;
            const u16* Vsrc = Vt0 + (size_t)(j0 >> 7) * 8192;
            const u16* Rsrc = rh + ((size_t)n * RPAD + jjbase_blk) * 64;
#pragma unroll
            for (int k = 0; k < 4; ++k)
                gl2lds16(Ksrc + (w * 4 + k) * 512 + lane * 8, Ks + (w * 4 + k) * 512);
#pragma unroll
            for (int k = 0; k < 4; ++k)
                gl2lds16(Vsrc + (w * 4 + k) * 512 + lane * 8, Vs + (w * 4 + k) * 512);
#pragma unroll
            for (int k = 0; k < 6; ++k)
                gl2lds16(Rsrc + (w * 6 + k) * 512 + lane * 8, Rs + (w * 6 + k) * 512);
        }
        __syncthreads();

        // ---- Bt: bacc[c] = qw . r, C-layout (rho = quad*4+reg, col = c*16+lr) ----
        f32x4 bacc[9];
#pragma unroll
        for (int c = 0; c < 9; ++c) bacc[c] = (f32x4)0.0f;
#pragma unroll
        for (int ks = 0; ks < 2; ++ks) {
#pragma unroll
            for (int c = 0; c < 9; ++c) {
                int row = c * 16 + lr + 48 - 16 * w;    // row in Rs
                s16x8 rf = *(const s16x8*)(Rs + row * 64 + (((ks * 4 + quad) + row) & 7) * 8);
                bacc[c] = __builtin_amdgcn_mfma_f32_16x16x32_bf16(qw[ks], rf, bacc[c], 0, 0, 0);
            }
        }
        // add rb2 per column
#pragma unroll
        for (int c = 0; c < 9; ++c) {
            int jj = jjbase_blk + 48 - 16 * w + c * 16 + lr;
            float rv = rb2[n * RPAD + jj];
            bacc[c][0] += rv; bacc[c][1] += rv; bacc[c][2] += rv; bacc[c][3] += rv;
        }
        // ---- rel-shift via ds_bpermute into the S accumulator ----
        f32x4 sacc[8];
#pragma unroll
        for (int r = 0; r < 4; ++r) {
            int rho = quad * 4 + r;
            int lrt_src = (lr + rho + 1) & 15;
            int up = lrt_src > rho;                  // source provides bacc[nt+1]
            int addr = (((lane & 48) | ((lr + 15 - rho) & 15)) << 2);
#pragma unroll
            for (int nt = 0; nt < 8; ++nt) {
                float v = up ? bacc[nt + 1][r] : bacc[nt][r];
                sacc[nt][r] = __int_as_float(
                    __builtin_amdgcn_ds_bpermute(addr, __float_as_int(v)));
            }
        }

        // ---- S = qw . K^T accumulated on top of the shifted bias ----
#pragma unroll
        for (int ks = 0; ks < 2; ++ks) {
#pragma unroll
            for (int nt = 0; nt < 8; ++nt) {
                int jloc = nt * 16 + lr;
                s16x8 kf = *(const s16x8*)(Ks + jloc * 64 + (((ks * 4 + quad) + jloc) & 7) * 8);
                sacc[nt] = __builtin_amdgcn_mfma_f32_16x16x32_bf16(qw[ks], kf, sacc[nt], 0, 0, 0);
            }
        }
        // ---- mask ----
#pragma unroll
        for (int nt = 0; nt < 8; ++nt) {
            int j = j0 + nt * 16 + lr;
#pragma unroll
            for (int r = 0; r < 4; ++r) {
                int i = wrow0 + quad * 4 + r;
                if (j > i + MLN) sacc[nt][r] = -INFINITY;
            }
        }

        // ---- online softmax (row-local across 16 lanes) ----
        float mx[4];
#pragma unroll
        for (int r = 0; r < 4; ++r) {
            mx[r] = sacc[0][r];
#pragma unroll
            for (int nt = 1; nt < 8; ++nt) mx[r] = fmaxf(mx[r], sacc[nt][r]);
        }
#pragma unroll
        for (int msk = 1; msk <= 8; msk <<= 1)
#pragma unroll
            for (int r = 0; r < 4; ++r)
                mx[r] = fmaxf(mx[r], __shfl_xor(mx[r], msk, 64));
        float al[4], mn[4];
#pragma unroll
        for (int r = 0; r < 4; ++r) {
            mn[r] = fmaxf(m_r[r], mx[r]);
            al[r] = __expf(m_r[r] - mn[r]);
            m_r[r] = mn[r];
#pragma unroll
            for (int dt = 0; dt < 4; ++dt) O[dt][r] *= al[r];
        }
        float ps[4] = {0.0f, 0.0f, 0.0f, 0.0f};
#pragma unroll
        for (int nt = 0; nt < 8; ++nt)
#pragma unroll
            for (int r = 0; r < 4; ++r) {
                float p = __expf(sacc[nt][r] - mn[r]);
                ps[r] += p;
                Pw[(quad * 4 + r) * 136 + nt * 16 + lr] = f2bf_fast(p);
            }
#pragma unroll
        for (int msk = 1; msk <= 8; msk <<= 1)
#pragma unroll
            for (int r = 0; r < 4; ++r) ps[r] += __shfl_xor(ps[r], msk, 64);
#pragma unroll
        for (int r = 0; r < 4; ++r) l_r[r] = l_r[r] * al[r] + ps[r];

        // ---- O += P . V ----
#pragma unroll
        for (int ks2 = 0; ks2 < 4; ++ks2) {
            s16x8 ap = *(const s16x8*)(Pw + lr * 136 + ks2 * 32 + quad * 8);
#pragma unroll
            for (int dt = 0; dt < 4; ++dt) {
                int d = dt * 16 + lr;
                s16x8 vb = *(const s16x8*)(Vs + d * 128 + (((ks2 * 4 + quad) + d) & 15) * 8);
                O[dt] = __builtin_amdgcn_mfma_f32_16x16x32_bf16(ap, vb, O[dt], 0, 0, 0);
            }
        }
    }

    // ---- epilogue: normalize, write ----
    float rL[4];
#pragma unroll
    for (int r = 0; r < 4; ++r) rL[r] = 1.0f / l_r[r];
#pragma unroll
    for (int dt = 0; dt < 4; ++dt)
#pragma unroll
        for (int r = 0; r < 4; ++r) {
            int i = wrow0 + quad * 4 + r;
            av[(size_t)(i * 2 + b) * DM + n * 64 + dt * 16 + lr] = f2bf(O[dt][r] * rL[r]);
        }
}

// ---------------- fused residual + LayerNorm ----------------
__global__ __launch_bounds__(256) void ln_fused(
    const float* __restrict__ x1, const float* __restrict__ x2,
    const float* __restrict__ gw, const float* __restrict__ bw,
    float* __restrict__ outf, u16* __restrict__ outb, int mode) {
    const int row = blockIdx.x, t = threadIdx.x, lane = t & 63, wv = t >> 6;
    __shared__ float red[8];
    float x[4];
    float s = 0.0f, s2 = 0.0f;
#pragma unroll
    for (int r = 0; r < 4; ++r) {
        int c = t + r * 256;
        float v = x1[(size_t)row * DM + c] + x2[(size_t)row * DM + c];
        x[r] = v;
        s += v;
        s2 += v * v;
    }
#pragma unroll
    for (int o = 32; o; o >>= 1) {
        s  += __shfl_xor(s, o, 64);
        s2 += __shfl_xor(s2, o, 64);
    }
    if (lane == 0) { red[wv] = s; red[4 + wv] = s2; }
    __syncthreads();
    s  = red[0] + red[1] + red[2] + red[3];
    s2 = red[4] + red[5] + red[6] + red[7];
    float mean = s * (1.0f / DM);
    float var  = s2 * (1.0f / DM) - mean * mean;
    float rstd = rsqrtf(var + 1e-5f);
#pragma unroll
    for (int r = 0; r < 4; ++r) {
        int c = t + r * 256;
        float y = gw[c] * (x[r] - mean) * rstd + bw[c];
        size_t idx = (size_t)row * DM + c;
        if (mode & 1) outf[idx] = y;
        if (mode & 2) outb[idx] = f2bf(y);
    }
}

extern "C" void kernel_launch(void* const* d_in, const int* in_sizes, int n_in,
                              void* d_out, int out_size, void* d_ws, size_t ws_size,
                              hipStream_t stream) {
    const float* w        = (const float*)d_in[0];
    const float* mems     = (const float*)d_in[1];
    const float* r_emb    = (const float*)d_in[2];
    const float* r_w_bias = (const float*)d_in[3];
    const float* r_bias   = (const float*)d_in[4];
    const float* qkv_w    = (const float*)d_in[5];
    const float* o_w      = (const float*)d_in[6];
    const float* ln1_g    = (const float*)d_in[7];
    const float* ln1_b    = (const float*)d_in[8];
    const float* ff_w1    = (const float*)d_in[9];
    const float* ff_b1    = (const float*)d_in[10];
    const float* ff_w2    = (const float*)d_in[11];
    const float* ff_b2    = (const float*)d_in[12];
    const float* ln2_g    = (const float*)d_in[13];
    const float* ln2_b    = (const float*)d_in[14];
    float* out = (float*)d_out;

    char* ws = (char*)d_ws;
    size_t off = 0;
    auto alloc = [&](size_t bytes) {
        size_t o = off;
        off += (bytes + 255) & ~(size_t)255;
        return o;
    };
    u16* cat_bf   = (u16*)(ws + alloc((size_t)KL * BATCH * DM * 2));
    u16* qkvw_bf  = (u16*)(ws + alloc((size_t)3 * NH * DH * DM * 2));
    u16* ow_bf    = (u16*)(ws + alloc((size_t)DM * NH * DH * 2));
    u16* w1_bf    = (u16*)(ws + alloc((size_t)DI * DM * 2));
    u16* w2_bf    = (u16*)(ws + alloc((size_t)DM * DI * 2));
    u16* rh_bf    = (u16*)(ws + alloc((size_t)NH * RPAD * 64 * 2));
    float* rb2    = (float*)(ws + alloc((size_t)NH * RPAD * 4));
    u16* Qb_bf    = (u16*)(ws + alloc((size_t)BATCH * QL * 1024 * 2));
    u16* Kh_bf    = (u16*)(ws + alloc((size_t)32 * 16 * 8192 * 2));
    u16* Vt2_bf   = (u16*)(ws + alloc((size_t)32 * 16 * 8192 * 2));
    u16* av_bf    = (u16*)(ws + alloc((size_t)QL * BATCH * DM * 2));
    float* ao_f   = (float*)(ws + alloc((size_t)QL * BATCH * DM * 4));
    float* h_f    = (float*)(ws + alloc((size_t)QL * BATCH * DM * 4));
    u16* h_bf     = (u16*)(ws + alloc((size_t)QL * BATCH * DM * 2));
    u16* inner_bf = (u16*)(ws + alloc((size_t)QL * BATCH * DI * 2));
    float* ffo_f  = (float*)(ws + alloc((size_t)QL * BATCH * DM * 4));
    (void)ws_size; (void)in_sizes; (void)n_in; (void)out_size;

    // 1) conversions + rel-bias prep
    cvt_cat<<<4096, 256, 0, stream>>>(mems, w, cat_bf);
    cvt_multi<<<2048, 256, 0, stream>>>(qkv_w, o_w, ff_w1, ff_w2,
                                        qkvw_bf, ow_bf, w1_bf, w2_bf);
    rcvt<<<dim3(72, 16), 256, 0, stream>>>(r_emb, rh_bf);
    rb2_prep<<<dim3(9, 16), 256, 0, stream>>>(r_emb, r_w_bias, r_bias, rb2);

    // 2) QKV projection with Q/Kh/Vt2 split epilogue
    gemm_s<128, 8><<<dim3(3072 / 128, (KL * BATCH) / 128), 256, 0, stream>>>(
        cat_bf, qkvw_bf, nullptr, nullptr, Qb_bf, Kh_bf, Vt2_bf, nullptr,
        KL * BATCH, 3072, DM);

    // 3) flash attention (staged tiles, bpermute rel-shift, XCD-local)
    flash_attn<<<512, 256, 0, stream>>>(Qb_bf, Kh_bf, Vt2_bf, rh_bf,
                                        r_w_bias, rb2, av_bf);

    // 4) output projection
    gemm_s<64, 0><<<dim3(DM / 64, (QL * BATCH) / 128), 256, 0, stream>>>(
        av_bf, ow_bf, ao_f, nullptr, nullptr, nullptr, nullptr, nullptr,
        QL * BATCH, DM, DM);

    // 5) h = LN(w + attn_out)
    ln_fused<<<QL * BATCH, 256, 0, stream>>>(w, ao_f, ln1_g, ln1_b, h_f, h_bf, 3);

    // 6) inner = relu(h * ff_w1^T + b1)
    gemm_s<128, 1 | 2 | 4><<<dim3(DI / 128, (QL * BATCH) / 128), 256, 0, stream>>>(
        h_bf, w1_bf, nullptr, inner_bf, nullptr, nullptr, nullptr, ff_b1,
        QL * BATCH, DI, DM);

    // 7) ff_out = inner * ff_w2^T + b2
    gemm_s<64, 2><<<dim3(DM / 64, (QL * BATCH) / 128), 256, 0, stream>>>(
        inner_bf, w2_bf, ffo_f, nullptr, nullptr, nullptr, nullptr, ff_b2,
        QL * BATCH, DM, DI);

    // 8) out = LN(h + ff_out)
    ln_fused<<<QL * BATCH, 256, 0, stream>>>(h_f, ffo_f, ln2_g, ln2_b, out, nullptr, 1);
}

// Round 8
// 344.853 us; speedup vs baseline: 2.2234x; 1.0916x over previous
//
#include <hip/hip_runtime.h>
#include <math.h>

#define DM    1024
#define NH    16
#define DH    64
#define DI    4096
#define QL    1024
#define MLN   1024
#define BATCH 2
#define KL    2048   // QL + MLN
#define RPAD  2304   // padded jj extent for rh / rb2

typedef unsigned short u16;
typedef short s16x8 __attribute__((ext_vector_type(8)));
typedef float f32x4 __attribute__((ext_vector_type(4)));

__device__ __forceinline__ u16 f2bf(float f) {
    union { float f; unsigned u; } v; v.f = f;
    unsigned u = v.u;
    unsigned r = (u + 0x7FFFu + ((u >> 16) & 1u)) >> 16;
    return (u16)r;
}
__device__ __forceinline__ u16 f2bf_fast(float f) {
    union { float f; unsigned u; } v; v.f = f;
    return (u16)((v.u + 0x8000u) >> 16);
}
__device__ __forceinline__ float bf2f(u16 h) {
    union { unsigned u; float f; } v; v.u = ((unsigned)h) << 16;
    return v.f;
}

__device__ __forceinline__ void gl2lds16(const void* g, void* l) {
    __builtin_amdgcn_global_load_lds(
        (const __attribute__((address_space(1))) void*)g,
        (__attribute__((address_space(3))) void*)l, 16, 0, 0);
}

// ---------------- fused weight fp32->bf16 (one launch) ----------------
__global__ __launch_bounds__(256) void cvt_multi(
    const float* __restrict__ a0, const float* __restrict__ a1,
    const float* __restrict__ a2, const float* __restrict__ a3,
    u16* __restrict__ o0, u16* __restrict__ o1,
    u16* __restrict__ o2, u16* __restrict__ o3) {
    int i = blockIdx.x * 256 + threadIdx.x;
    int stride = gridDim.x * 256;
    for (; i < 3145728; i += stride) {
        const float* src; u16* dst; int k;
        if (i < 786432)       { src = a0; dst = o0; k = i; }
        else if (i < 1048576) { src = a1; dst = o1; k = i - 786432; }
        else if (i < 2097152) { src = a2; dst = o2; k = i - 1048576; }
        else                  { src = a3; dst = o3; k = i - 2097152; }
        float4 v = ((const float4*)src)[k];
        ushort4 o = {f2bf(v.x), f2bf(v.y), f2bf(v.z), f2bf(v.w)};
        ((ushort4*)dst)[k] = o;
    }
}

// cat in batch-major layout: cat[b][kpos][:] from mems[k][b][:] / w[i][b][:]
__global__ __launch_bounds__(256) void cvt_cat(const float* __restrict__ mems,
                                               const float* __restrict__ w,
                                               u16* __restrict__ cat) {
    int id = blockIdx.x * 256 + threadIdx.x;
    int c4 = (id & 255) * 4;
    int row = id >> 8;
    int b = row >> 11, kpos = row & 2047;
    const float* src = (kpos < QL)
        ? mems + ((size_t)kpos * BATCH + b) * DM + c4
        : w + ((size_t)(kpos - QL) * BATCH + b) * DM + c4;
    float4 v = *(const float4*)src;
    ushort4 o = {f2bf(v.x), f2bf(v.y), f2bf(v.z), f2bf(v.w)};
    *(ushort4*)(cat + (size_t)row * DM + c4) = o;
}

// rh[n][jj][64d], granule-swizzled: stored granule gs holds logical granule
// gl=(gs-jj)&7 (16B granules). jj>=KL -> zeros. grid dim3(72,16).
__global__ __launch_bounds__(256) void rcvt(const float* __restrict__ r_emb,
                                            u16* __restrict__ rh) {
    int id = blockIdx.x * 256 + threadIdx.x;
    int n = blockIdx.y;
    int jj = id >> 3, gs = id & 7;
    s16x8 o;
    if (jj < KL) {
        int gl = (gs - jj) & 7;
        const float* s = r_emb + (size_t)jj * DM + n * 64 + gl * 8;
#pragma unroll
        for (int k = 0; k < 8; ++k) o[k] = (short)f2bf(s[k]);
    } else {
#pragma unroll
        for (int k = 0; k < 8; ++k) o[k] = 0;
    }
    *(s16x8*)(rh + ((size_t)n * RPAD + jj) * 64 + gs * 8) = o;
}

// rb2[n][jj] = 0.125*(r_bias[jj,n] - r_w_bias[n,:].dot(r_emb[jj,n,:])), padded.
__global__ __launch_bounds__(256) void rb2_prep(const float* __restrict__ r_emb,
                                                const float* __restrict__ r_w_bias,
                                                const float* __restrict__ r_bias,
                                                float* __restrict__ rb2) {
    int jj = blockIdx.x * 256 + threadIdx.x;
    int n = blockIdx.y;
    if (jj >= RPAD) return;
    float v = 0.0f;
    if (jj < KL) {
        float dot = 0.0f;
#pragma unroll 8
        for (int d = 0; d < 64; ++d)
            dot += r_w_bias[n * 64 + d] * r_emb[(size_t)jj * DM + n * 64 + d];
        v = 0.125f * (r_bias[jj * NH + n] - dot);
    }
    rb2[n * RPAD + jj] = v;
}

// ---------------- staged GEMM: C[M,*] = A[M,K] * B[*,K]^T ----------------
// FLAGS: 1=bf16 out, 2=bias, 4=relu, 8=QKV split epilogue (Q/Kh/Vt2 layouts)
template <int BN, int FLAGS>
__global__ __launch_bounds__(256) void gemm_s(const u16* __restrict__ A,
                                              const u16* __restrict__ B,
                                              float* __restrict__ Cf,
                                              u16* __restrict__ Cb,
                                              u16* __restrict__ Qo,
                                              u16* __restrict__ Ko,
                                              u16* __restrict__ Vo,
                                              const float* __restrict__ bias,
                                              int M, int N_out, int K) {
    constexpr int WN = BN / 2;
    constexpr int TN = WN / 16;
    __shared__ u16 As[128 * 32];
    __shared__ u16 Bs[BN * 32];

    const int t = threadIdx.x;
    const int lane = t & 63, wid = t >> 6;
    const int wm = wid >> 1, wn = wid & 1;
    const int lr = lane & 15, quad = lane >> 4;
    const int m_blk = blockIdx.y * 128;
    const int n_blk = blockIdx.x * BN;
    const int srow = t >> 2;
    const int skc  = (t & 3) * 8;

    f32x4 acc[4][TN];
#pragma unroll
    for (int i = 0; i < 4; ++i)
#pragma unroll
        for (int j = 0; j < TN; ++j) acc[i][j] = (f32x4)0.0f;

    for (int k0 = 0; k0 < K; k0 += 32) {
        __syncthreads();
        gl2lds16(A + (size_t)(m_blk + srow) * K + k0 + skc, As + wid * 512);
        gl2lds16(A + (size_t)(m_blk + 64 + srow) * K + k0 + skc, As + 2048 + wid * 512);
        gl2lds16(B + (size_t)(n_blk + srow) * K + k0 + skc, Bs + wid * 512);
        if (BN == 128)
            gl2lds16(B + (size_t)(n_blk + 64 + srow) * K + k0 + skc, Bs + 2048 + wid * 512);
        __syncthreads();

        s16x8 a[4], b[TN];
#pragma unroll
        for (int i = 0; i < 4; ++i)
            a[i] = *(const s16x8*)(As + (wm * 64 + i * 16 + lr) * 32 + quad * 8);
#pragma unroll
        for (int j = 0; j < TN; ++j)
            b[j] = *(const s16x8*)(Bs + (wn * WN + j * 16 + lr) * 32 + quad * 8);
#pragma unroll
        for (int i = 0; i < 4; ++i)
#pragma unroll
            for (int j = 0; j < TN; ++j)
                acc[i][j] = __builtin_amdgcn_mfma_f32_16x16x32_bf16(
                    a[i], b[j], acc[i][j], 0, 0, 0);
    }

#pragma unroll
    for (int i = 0; i < 4; ++i) {
#pragma unroll
        for (int j = 0; j < TN; ++j) {
            int row0 = m_blk + wm * 64 + i * 16 + quad * 4;
            int col  = n_blk + wn * WN + j * 16 + lr;
            if (FLAGS & 8) {
                int b_ = row0 >> 11, kpos = row0 & 2047;
                if (col < 1024) {
                    if (kpos >= QL) {
                        u16* q = Qo + ((size_t)(b_ * QL + kpos - QL)) * 1024 + col;
#pragma unroll
                        for (int r = 0; r < 4; ++r) q[r * 1024] = f2bf(acc[i][j][r]);
                    }
                } else if (col < 2048) {
                    int d = col & 63, nh = (col >> 6) & 15;
                    size_t base = ((size_t)((b_ * 16 + nh) * 16 + (kpos >> 7))) * 8192;
#pragma unroll
                    for (int r = 0; r < 4; ++r) {
                        int jl = (kpos & 127) + r;
                        Ko[base + jl * 64 + (((d >> 3) + jl) & 7) * 8 + (d & 7)] =
                            f2bf(acc[i][j][r]);
                    }
                } else {
                    int d = col & 63, nh = (col >> 6) & 15;
                    int jl = kpos & 127;
                    size_t base = ((size_t)((b_ * 16 + nh) * 16 + (kpos >> 7))) * 8192
                                  + d * 128 + (((jl >> 3) + d) & 15) * 8 + (jl & 7);
                    ushort4 o = {f2bf(acc[i][j][0]), f2bf(acc[i][j][1]),
                                 f2bf(acc[i][j][2]), f2bf(acc[i][j][3])};
                    *(ushort4*)(Vo + base) = o;
                }
            } else {
                float bv = (FLAGS & 2) ? bias[col] : 0.0f;
#pragma unroll
                for (int r = 0; r < 4; ++r) {
                    float v = acc[i][j][r] + bv;
                    if (FLAGS & 4) v = fmaxf(v, 0.0f);
                    size_t idx = (size_t)(row0 + r) * N_out + col;
                    if (FLAGS & 1) Cb[idx] = f2bf(v);
                    else           Cf[idx] = v;
                }
            }
        }
    }
}

// ---------------- split-K GEMM: P[kz][M,N] = A[M,Kc] * B[N,Kc]^T ----------------
// grid (N/64, M/128, SPLIT); fp32 partials, reduced inside ln_fused_k.
// 2 blocks/CU (vs 1 for the monolithic BN=64 GEMM) restores latency hiding.
template <int SPLIT>
__global__ __launch_bounds__(256) void gemm_sk(const u16* __restrict__ A,
                                               const u16* __restrict__ B,
                                               float* __restrict__ P,
                                               int M, int N_out, int K) {
    __shared__ u16 As[128 * 32];
    __shared__ u16 Bs[64 * 32];

    const int t = threadIdx.x;
    const int lane = t & 63, wid = t >> 6;
    const int wm = wid >> 1, wn = wid & 1;
    const int lr = lane & 15, quad = lane >> 4;
    const int m_blk = blockIdx.y * 128;
    const int n_blk = blockIdx.x * 64;
    const int kz = blockIdx.z;
    const int Kc = K / SPLIT;
    const int kbeg = kz * Kc, kend = kbeg + Kc;
    const int srow = t >> 2;
    const int skc  = (t & 3) * 8;

    f32x4 acc[4][2];
#pragma unroll
    for (int i = 0; i < 4; ++i)
#pragma unroll
        for (int j = 0; j < 2; ++j) acc[i][j] = (f32x4)0.0f;

    for (int k0 = kbeg; k0 < kend; k0 += 32) {
        __syncthreads();
        gl2lds16(A + (size_t)(m_blk + srow) * K + k0 + skc, As + wid * 512);
        gl2lds16(A + (size_t)(m_blk + 64 + srow) * K + k0 + skc, As + 2048 + wid * 512);
        gl2lds16(B + (size_t)(n_blk + srow) * K + k0 + skc, Bs + wid * 512);
        __syncthreads();

        s16x8 a[4], b[2];
#pragma unroll
        for (int i = 0; i < 4; ++i)
            a[i] = *(const s16x8*)(As + (wm * 64 + i * 16 + lr) * 32 + quad * 8);
#pragma unroll
        for (int j = 0; j < 2; ++j)
            b[j] = *(const s16x8*)(Bs + (wn * 32 + j * 16 + lr) * 32 + quad * 8);
#pragma unroll
        for (int i = 0; i < 4; ++i)
#pragma unroll
            for (int j = 0; j < 2; ++j)
                acc[i][j] = __builtin_amdgcn_mfma_f32_16x16x32_bf16(
                    a[i], b[j], acc[i][j], 0, 0, 0);
    }

    float* Pz = P + (size_t)kz * M * N_out;
#pragma unroll
    for (int i = 0; i < 4; ++i)
#pragma unroll
        for (int j = 0; j < 2; ++j) {
            int row0 = m_blk + wm * 64 + i * 16 + quad * 4;
            int col  = n_blk + wn * 32 + j * 16 + lr;
#pragma unroll
            for (int r = 0; r < 4; ++r)
                Pz[(size_t)(row0 + r) * N_out + col] = acc[i][j][r];
        }
}

// ---------------- flash attention: staged tiles + bpermute rel-shift ----------------
__global__ __launch_bounds__(256, 2) void flash_attn(
    const u16* __restrict__ Qb, const u16* __restrict__ Kh,
    const u16* __restrict__ Vt2, const u16* __restrict__ rh,
    const float* __restrict__ r_w_bias, const float* __restrict__ rb2,
    u16* __restrict__ av) {
    const int bn = blockIdx.x & 31;
    const int i0 = (blockIdx.x >> 5) * 64;
    const int b = bn >> 4, n = bn & 15;
    const int t = threadIdx.x;
    const int lane = t & 63, w = t >> 6;
    const int lr = lane & 15, quad = lane >> 4;

    __shared__ __align__(16) u16 Ks[128 * 64];
    __shared__ __align__(16) u16 Vs[64 * 128];
    __shared__ __align__(16) u16 Rs[192 * 64];
    __shared__ __align__(16) u16 Pw_all[4 * 16 * 136];
    u16* Pw = Pw_all + w * (16 * 136);

    const int wrow0 = i0 + w * 16;

    s16x8 qw[2];
#pragma unroll
    for (int ks = 0; ks < 2; ++ks) {
        const u16* qp = Qb + ((size_t)(b * QL + wrow0 + lr)) * 1024 + n * 64 + ks * 32 + quad * 8;
        s16x8 qv = *(const s16x8*)qp;
        s16x8 o;
#pragma unroll
        for (int k = 0; k < 8; ++k) {
            float f = bf2f((u16)qv[k]) + r_w_bias[n * 64 + ks * 32 + quad * 8 + k];
            o[k] = (short)f2bf(f * 0.125f);
        }
        qw[ks] = o;
    }

    f32x4 O[4];
    float m_r[4], l_r[4];
#pragma unroll
    for (int x = 0; x < 4; ++x) {
        O[x] = (f32x4)0.0f;
        m_r[x] = -INFINITY;
        l_r[x] = 0.0f;
    }

    const u16* Kt0 = Kh + (size_t)bn * 16 * 8192;
    const u16* Vt0 = Vt2 + (size_t)bn * 16 * 8192;
    const int jend = i0 + 64 + MLN;

    for (int j0 = 0; j0 < jend; j0 += 128) {
        const int jjbase_blk = j0 + 960 - i0;
        __syncthreads();
        {
            const u16* Ksrc = Kt0 + (size_t)(j0 >> 7) * 8192;
            const u16* Vsrc = Vt0 + (size_t)(j0 >> 7) * 8192;
            const u16* Rsrc = rh + ((size_t)n * RPAD + jjbase_blk) * 64;
#pragma unroll
            for (int k = 0; k < 4; ++k)
                gl2lds16(Ksrc + (w * 4 + k) * 512 + lane * 8, Ks + (w * 4 + k) * 512);
#pragma unroll
            for (int k = 0; k < 4; ++k)
                gl2lds16(Vsrc + (w * 4 + k) * 512 + lane * 8, Vs + (w * 4 + k) * 512);
#pragma unroll
            for (int k = 0; k < 6; ++k)
                gl2lds16(Rsrc + (w * 6 + k) * 512 + lane * 8, Rs + (w * 6 + k) * 512);
        }
        __syncthreads();

        f32x4 bacc[9];
#pragma unroll
        for (int c = 0; c < 9; ++c) bacc[c] = (f32x4)0.0f;
#pragma unroll
        for (int ks = 0; ks < 2; ++ks) {
#pragma unroll
            for (int c = 0; c < 9; ++c) {
                int row = c * 16 + lr + 48 - 16 * w;
                s16x8 rf = *(const s16x8*)(Rs + row * 64 + (((ks * 4 + quad) + row) & 7) * 8);
                bacc[c] = __builtin_amdgcn_mfma_f32_16x16x32_bf16(qw[ks], rf, bacc[c], 0, 0, 0);
            }
        }
#pragma unroll
        for (int c = 0; c < 9; ++c) {
            int jj = jjbase_blk + 48 - 16 * w + c * 16 + lr;
            float rv = rb2[n * RPAD + jj];
            bacc[c][0] += rv; bacc[c][1] += rv; bacc[c][2] += rv; bacc[c][3] += rv;
        }
        f32x4 sacc[8];
#pragma unroll
        for (int r = 0; r < 4; ++r) {
            int rho = quad * 4 + r;
            int lrt_src = (lr + rho + 1) & 15;
            int up = lrt_src > rho;
            int addr = (((lane & 48) | ((lr + 15 - rho) & 15)) << 2);
#pragma unroll
            for (int nt = 0; nt < 8; ++nt) {
                float v = up ? bacc[nt + 1][r] : bacc[nt][r];
                sacc[nt][r] = __int_as_float(
                    __builtin_amdgcn_ds_bpermute(addr, __float_as_int(v)));
            }
        }

#pragma unroll
        for (int ks = 0; ks < 2; ++ks) {
#pragma unroll
            for (int nt = 0; nt < 8; ++nt) {
                int jloc = nt * 16 + lr;
                s16x8 kf = *(const s16x8*)(Ks + jloc * 64 + (((ks * 4 + quad) + jloc) & 7) * 8);
                sacc[nt] = __builtin_amdgcn_mfma_f32_16x16x32_bf16(qw[ks], kf, sacc[nt], 0, 0, 0);
            }
        }
#pragma unroll
        for (int nt = 0; nt < 8; ++nt) {
            int j = j0 + nt * 16 + lr;
#pragma unroll
            for (int r = 0; r < 4; ++r) {
                int i = wrow0 + quad * 4 + r;
                if (j > i + MLN) sacc[nt][r] = -INFINITY;
            }
        }

        float mx[4];
#pragma unroll
        for (int r = 0; r < 4; ++r) {
            mx[r] = sacc[0][r];
#pragma unroll
            for (int nt = 1; nt < 8; ++nt) mx[r] = fmaxf(mx[r], sacc[nt][r]);
        }
#pragma unroll
        for (int msk = 1; msk <= 8; msk <<= 1)
#pragma unroll
            for (int r = 0; r < 4; ++r)
                mx[r] = fmaxf(mx[r], __shfl_xor(mx[r], msk, 64));
        float al[4], mn[4];
#pragma unroll
        for (int r = 0; r < 4; ++r) {
            mn[r] = fmaxf(m_r[r], mx[r]);
            al[r] = __expf(m_r[r] - mn[r]);
            m_r[r] = mn[r];
#pragma unroll
            for (int dt = 0; dt < 4; ++dt) O[dt][r] *= al[r];
        }
        float ps[4] = {0.0f, 0.0f, 0.0f, 0.0f};
#pragma unroll
        for (int nt = 0; nt < 8; ++nt)
#pragma unroll
            for (int r = 0; r < 4; ++r) {
                float p = __expf(sacc[nt][r] - mn[r]);
                ps[r] += p;
                Pw[(quad * 4 + r) * 136 + nt * 16 + lr] = f2bf_fast(p);
            }
#pragma unroll
        for (int msk = 1; msk <= 8; msk <<= 1)
#pragma unroll
            for (int r = 0; r < 4; ++r) ps[r] += __shfl_xor(ps[r], msk, 64);
#pragma unroll
        for (int r = 0; r < 4; ++r) l_r[r] = l_r[r] * al[r] + ps[r];

#pragma unroll
        for (int ks2 = 0; ks2 < 4; ++ks2) {
            s16x8 ap = *(const s16x8*)(Pw + lr * 136 + ks2 * 32 + quad * 8);
#pragma unroll
            for (int dt = 0; dt < 4; ++dt) {
                int d = dt * 16 + lr;
                s16x8 vb = *(const s16x8*)(Vs + d * 128 + (((ks2 * 4 + quad) + d) & 15) * 8);
                O[dt] = __builtin_amdgcn_mfma_f32_16x16x32_bf16(ap, vb, O[dt], 0, 0, 0);
            }
        }
    }

    float rL[4];
#pragma unroll
    for (int r = 0; r < 4; ++r) rL[r] = 1.0f / l_r[r];
#pragma unroll
    for (int dt = 0; dt < 4; ++dt)
#pragma unroll
        for (int r = 0; r < 4; ++r) {
            int i = wrow0 + quad * 4 + r;
            av[(size_t)(i * 2 + b) * DM + n * 64 + dt * 16 + lr] = f2bf(O[dt][r] * rL[r]);
        }
}

// ---------------- fused split-K reduce + bias + residual + LayerNorm ----------------
// v = x1 + sum_{p<2} P[p][idx] (+bias); then LN. mode: 1=fp32 out, 2=bf16 out.
__global__ __launch_bounds__(256) void ln_fused_k(
    const float* __restrict__ x1, const float* __restrict__ P,
    const float* __restrict__ bias,
    const float* __restrict__ gw, const float* __restrict__ bw,
    float* __restrict__ outf, u16* __restrict__ outb, int mode) {
    const int row = blockIdx.x, t = threadIdx.x, lane = t & 63, wv = t >> 6;
    const size_t MN = (size_t)QL * BATCH * DM;
    __shared__ float red[8];
    float x[4];
    float s = 0.0f, s2 = 0.0f;
#pragma unroll
    for (int r = 0; r < 4; ++r) {
        int c = t + r * 256;
        size_t idx = (size_t)row * DM + c;
        float v = x1[idx] + P[idx] + P[MN + idx];
        if (bias) v += bias[c];
        x[r] = v;
        s += v;
        s2 += v * v;
    }
#pragma unroll
    for (int o = 32; o; o >>= 1) {
        s  += __shfl_xor(s, o, 64);
        s2 += __shfl_xor(s2, o, 64);
    }
    if (lane == 0) { red[wv] = s; red[4 + wv] = s2; }
    __syncthreads();
    s  = red[0] + red[1] + red[2] + red[3];
    s2 = red[4] + red[5] + red[6] + red[7];
    float mean = s * (1.0f / DM);
    float var  = s2 * (1.0f / DM) - mean * mean;
    float rstd = rsqrtf(var + 1e-5f);
#pragma unroll
    for (int r = 0; r < 4; ++r) {
        int c = t + r * 256;
        float y = gw[c] * (x[r] - mean) * rstd + bw[c];
        size_t idx = (size_t)row * DM + c;
        if (mode & 1) outf[idx] = y;
        if (mode & 2) outb[idx] = f2bf(y);
    }
}

extern "C" void kernel_launch(void* const* d_in, const int* in_sizes, int n_in,
                              void* d_out, int out_size, void* d_ws, size_t ws_size,
                              hipStream_t stream) {
    const float* w        = (const float*)d_in[0];
    const float* mems     = (const float*)d_in[1];
    const float* r_emb    = (const float*)d_in[2];
    const float* r_w_bias = (const float*)d_in[3];
    const float* r_bias   = (const float*)d_in[4];
    const float* qkv_w    = (const float*)d_in[5];
    const float* o_w      = (const float*)d_in[6];
    const float* ln1_g    = (const float*)d_in[7];
    const float* ln1_b    = (const float*)d_in[8];
    const float* ff_w1    = (const float*)d_in[9];
    const float* ff_b1    = (const float*)d_in[10];
    const float* ff_w2    = (const float*)d_in[11];
    const float* ff_b2    = (const float*)d_in[12];
    const float* ln2_g    = (const float*)d_in[13];
    const float* ln2_b    = (const float*)d_in[14];
    float* out = (float*)d_out;

    char* ws = (char*)d_ws;
    size_t off = 0;
    auto alloc = [&](size_t bytes) {
        size_t o = off;
        off += (bytes + 255) & ~(size_t)255;
        return o;
    };
    u16* cat_bf   = (u16*)(ws + alloc((size_t)KL * BATCH * DM * 2));
    u16* qkvw_bf  = (u16*)(ws + alloc((size_t)3 * NH * DH * DM * 2));
    u16* ow_bf    = (u16*)(ws + alloc((size_t)DM * NH * DH * 2));
    u16* w1_bf    = (u16*)(ws + alloc((size_t)DI * DM * 2));
    u16* w2_bf    = (u16*)(ws + alloc((size_t)DM * DI * 2));
    u16* rh_bf    = (u16*)(ws + alloc((size_t)NH * RPAD * 64 * 2));
    float* rb2    = (float*)(ws + alloc((size_t)NH * RPAD * 4));
    u16* Qb_bf    = (u16*)(ws + alloc((size_t)BATCH * QL * 1024 * 2));
    u16* Kh_bf    = (u16*)(ws + alloc((size_t)32 * 16 * 8192 * 2));   // 8 MB
    u16* Vt2_bf   = (u16*)(ws + alloc((size_t)32 * 16 * 8192 * 2));   // 8 MB (contig)
    u16* av_bf    = (u16*)(ws + alloc((size_t)QL * BATCH * DM * 2));
    float* h_f    = (float*)(ws + alloc((size_t)QL * BATCH * DM * 4));
    u16* h_bf     = (u16*)(ws + alloc((size_t)QL * BATCH * DM * 2));
    u16* inner_bf = (u16*)(ws + alloc((size_t)QL * BATCH * DI * 2));
    (void)ws_size; (void)in_sizes; (void)n_in; (void)out_size;

    // split-K partials (2 x 8 MB fp32) overlay the Kh/Vt2 region, which is
    // dead after flash_attn completes (stream-ordered).
    float* Pk = (float*)Kh_bf;

    // 1) conversions + rel-bias prep
    cvt_cat<<<4096, 256, 0, stream>>>(mems, w, cat_bf);
    cvt_multi<<<2048, 256, 0, stream>>>(qkv_w, o_w, ff_w1, ff_w2,
                                        qkvw_bf, ow_bf, w1_bf, w2_bf);
    rcvt<<<dim3(72, 16), 256, 0, stream>>>(r_emb, rh_bf);
    rb2_prep<<<dim3(9, 16), 256, 0, stream>>>(r_emb, r_w_bias, r_bias, rb2);

    // 2) QKV projection with Q/Kh/Vt2 split epilogue
    gemm_s<128, 8><<<dim3(3072 / 128, (KL * BATCH) / 128), 256, 0, stream>>>(
        cat_bf, qkvw_bf, nullptr, nullptr, Qb_bf, Kh_bf, Vt2_bf, nullptr,
        KL * BATCH, 3072, DM);

    // 3) flash attention
    flash_attn<<<512, 256, 0, stream>>>(Qb_bf, Kh_bf, Vt2_bf, rh_bf,
                                        r_w_bias, rb2, av_bf);

    // 4) output projection, split-K x2 -> fp32 partials (2 blocks/CU)
    gemm_sk<2><<<dim3(DM / 64, (QL * BATCH) / 128, 2), 256, 0, stream>>>(
        av_bf, ow_bf, Pk, QL * BATCH, DM, DM);

    // 5) h = LN(w + P0 + P1)
    ln_fused_k<<<QL * BATCH, 256, 0, stream>>>(w, Pk, nullptr, ln1_g, ln1_b,
                                               h_f, h_bf, 3);

    // 6) inner = relu(h * ff_w1^T + b1)
    gemm_s<128, 1 | 2 | 4><<<dim3(DI / 128, (QL * BATCH) / 128), 256, 0, stream>>>(
        h_bf, w1_bf, nullptr, inner_bf, nullptr, nullptr, nullptr, ff_b1,
        QL * BATCH, DI, DM);

    // 7) ff_out partials, split-K x2 (K=2048 each, 2 blocks/CU)
    gemm_sk<2><<<dim3(DM / 64, (QL * BATCH) / 128, 2), 256, 0, stream>>>(
        inner_bf, w2_bf, Pk, QL * BATCH, DM, DI);

    // 8) out = LN(h + P0 + P1 + b2)
    ln_fused_k<<<QL * BATCH, 256, 0, stream>>>(h_f, Pk, ff_b2, ln2_g, ln2_b,
                                               out, nullptr, 1);
}